// Round 1
// baseline (2859.619 us; speedup 1.0000x reference)
//
#include <hip/hip_runtime.h>

#define NN 100000
#define NE 1600000
#define DD 128

// ---------------- degree count ----------------
__global__ void k_count(const int* __restrict__ col, int* __restrict__ deg) {
    int i = blockIdx.x * blockDim.x + threadIdx.x;
    if (i < NE) atomicAdd(&deg[col[i]], 1);
}

// ---------------- dinv = (deg+1)^-0.5 ----------------
__global__ void k_dinv(const int* __restrict__ deg, float* __restrict__ dinv) {
    int i = blockIdx.x * blockDim.x + threadIdx.x;
    if (i < NN) dinv[i] = 1.0f / sqrtf((float)(deg[i] + 1));
}

// ---------------- agg init with self-loop term ----------------
__global__ void k_init_agg(const float* __restrict__ x, const float* __restrict__ dinv,
                           float* __restrict__ agg) {
    int i = blockIdx.x * blockDim.x + threadIdx.x;  // over NN*DD/4 float4s
    if (i < NN * (DD / 4)) {
        int node = i / (DD / 4);
        float s = dinv[node];
        s *= s;
        float4 v = ((const float4*)x)[i];
        v.x *= s; v.y *= s; v.z *= s; v.w *= s;
        ((float4*)agg)[i] = v;
    }
}

// ---------------- edge scatter: agg[c] += dinv[r]*dinv[c]*x[r] ----------------
// 32 threads per edge, 4 floats (one float4 load, 4 scalar f32 atomics) each.
__global__ void k_scatter(const int* __restrict__ row, const int* __restrict__ col,
                          const float* __restrict__ x, const float* __restrict__ dinv,
                          float* __restrict__ agg) {
    long long gid = (long long)blockIdx.x * blockDim.x + threadIdx.x;
    int lane = (int)(gid & 31);
    long long e = gid >> 5;
    if (e < NE) {
        int r = row[e];
        int c = col[e];
        float s = dinv[r] * dinv[c];
        float4 v = ((const float4*)(x + (size_t)r * DD))[lane];
        float* ac = agg + (size_t)c * DD + lane * 4;
        unsafeAtomicAdd(ac + 0, s * v.x);
        unsafeAtomicAdd(ac + 1, s * v.y);
        unsafeAtomicAdd(ac + 2, s * v.z);
        unsafeAtomicAdd(ac + 3, s * v.w);
    }
}

// ---------------- W -> Wt (Wt[k][c] = W[c][k]) ----------------
__global__ void k_transpose_w(const float* __restrict__ W, float* __restrict__ Wt) {
    int c = blockIdx.x;   // 128 blocks
    int k = threadIdx.x;  // 128 threads
    Wt[k * DD + c] = W[c * DD + k];
}

// ---------------- in-place GEMM + bias + relu + residual ----------------
// out (== agg buffer): out[r] = x[r] + relu(agg[r] @ Wt + b)
// Block: 256 threads, 64 rows. Group = 32 lanes owns 8 rows x its 4 cols.
__global__ __launch_bounds__(256) void k_gemm(const float* __restrict__ x,
                                              const float* __restrict__ Wt,
                                              const float* __restrict__ bias,
                                              float* __restrict__ out) {
    __shared__ float wt[DD * DD];  // 64 KB
    int t = threadIdx.x;
    for (int i = t; i < DD * DD / 4; i += 256)
        ((float4*)wt)[i] = ((const float4*)Wt)[i];
    __syncthreads();

    int grp = t >> 5;             // 0..7
    int c4  = (t & 31) * 4;       // 4 consecutive output cols
    int rbase = blockIdx.x * 64 + grp * 8;

    float acc[8][4];
#pragma unroll
    for (int i = 0; i < 8; i++)
#pragma unroll
        for (int j = 0; j < 4; j++) acc[i][j] = 0.0f;

    for (int k = 0; k < DD; k += 4) {
        float4 w0 = *(const float4*)&wt[(k + 0) * DD + c4];
        float4 w1 = *(const float4*)&wt[(k + 1) * DD + c4];
        float4 w2 = *(const float4*)&wt[(k + 2) * DD + c4];
        float4 w3 = *(const float4*)&wt[(k + 3) * DD + c4];
#pragma unroll
        for (int i = 0; i < 8; i++) {
            int rr = rbase + i;
            rr = rr < NN ? rr : NN - 1;  // clamp; clamped rows never written
            float4 a = *(const float4*)&out[(size_t)rr * DD + k];
            acc[i][0] += a.x * w0.x + a.y * w1.x + a.z * w2.x + a.w * w3.x;
            acc[i][1] += a.x * w0.y + a.y * w1.y + a.z * w2.y + a.w * w3.y;
            acc[i][2] += a.x * w0.z + a.y * w1.z + a.z * w2.z + a.w * w3.z;
            acc[i][3] += a.x * w0.w + a.y * w1.w + a.z * w2.w + a.w * w3.w;
        }
    }

    float4 bv = *(const float4*)&bias[c4];
#pragma unroll
    for (int i = 0; i < 8; i++) {
        int r = rbase + i;
        if (r < NN) {
            float4 xv = *(const float4*)&x[(size_t)r * DD + c4];
            float4 o;
            o.x = xv.x + fmaxf(acc[i][0] + bv.x, 0.0f);
            o.y = xv.y + fmaxf(acc[i][1] + bv.y, 0.0f);
            o.z = xv.z + fmaxf(acc[i][2] + bv.z, 0.0f);
            o.w = xv.w + fmaxf(acc[i][3] + bv.w, 0.0f);
            *(float4*)&out[(size_t)r * DD + c4] = o;
        }
    }
}

extern "C" void kernel_launch(void* const* d_in, const int* in_sizes, int n_in,
                              void* d_out, int out_size, void* d_ws, size_t ws_size,
                              hipStream_t stream) {
    const float* x   = (const float*)d_in[0];
    const int*   ei  = (const int*)d_in[1];
    const float* W   = (const float*)d_in[2];
    const float* b   = (const float*)d_in[3];
    const int* row = ei;        // edge_index[0] = source
    const int* col = ei + NE;   // edge_index[1] = target

    float* out = (float*)d_out;

    char* ws = (char*)d_ws;
    int*   deg  = (int*)ws;                              // NN ints
    float* dinv = (float*)(ws + (size_t)NN * 4);         // NN floats
    float* Wt   = (float*)(ws + (size_t)2 * NN * 4);     // 128*128 floats (offset 800000, 16B aligned)

    hipMemsetAsync(deg, 0, NN * sizeof(int), stream);

    k_count<<<(NE + 255) / 256, 256, 0, stream>>>(col, deg);
    k_dinv<<<(NN + 255) / 256, 256, 0, stream>>>(deg, dinv);
    k_init_agg<<<(NN * (DD / 4) + 255) / 256, 256, 0, stream>>>(x, dinv, out);

    long long scatter_threads = (long long)NE * 32;
    int scatter_blocks = (int)((scatter_threads + 255) / 256);
    k_scatter<<<scatter_blocks, 256, 0, stream>>>(row, col, x, dinv, out);

    k_transpose_w<<<DD, DD, 0, stream>>>(W, Wt);
    k_gemm<<<(NN + 63) / 64, 256, 0, stream>>>(x, Wt, b, out);
}

// Round 2
// 556.061 us; speedup vs baseline: 5.1426x; 5.1426x over previous
//
#include <hip/hip_runtime.h>

#define NN 100000
#define NE 1600000
#define DD 128

// ---------------- degree count (in-degree of col) ----------------
__global__ void k_count(const int* __restrict__ col, int* __restrict__ deg) {
    int i = blockIdx.x * blockDim.x + threadIdx.x;
    if (i < NE) atomicAdd(&deg[col[i]], 1);
}

// ---------------- dinv = (deg+1)^-0.5  (self-loop adds 1) ----------------
__global__ void k_dinv(const int* __restrict__ deg, float* __restrict__ dinv) {
    int i = blockIdx.x * blockDim.x + threadIdx.x;
    if (i < NN) dinv[i] = 1.0f / sqrtf((float)(deg[i] + 1));
}

// ---------------- exclusive scan of deg -> rowptr (single block) ----------------
__global__ __launch_bounds__(1024) void k_scan(const int* __restrict__ deg,
                                               int* __restrict__ rowptr) {
    __shared__ int part[1024];
    int t = threadIdx.x;
    const int chunk = (NN + 1023) / 1024;  // 98
    int beg = t * chunk;
    int end = beg + chunk < NN ? beg + chunk : NN;
    int s = 0;
    for (int i = beg; i < end; ++i) s += deg[i];
    part[t] = s;
    __syncthreads();
    for (int off = 1; off < 1024; off <<= 1) {
        int v = (t >= off) ? part[t - off] : 0;
        __syncthreads();
        part[t] += v;
        __syncthreads();
    }
    int excl = (t == 0) ? 0 : part[t - 1];
    for (int i = beg; i < end; ++i) {
        rowptr[i] = excl;
        excl += deg[i];
    }
    if (t == 1023) rowptr[NN] = part[1023];  // == NE
}

// ---------------- fill CSR edge lists: esrc[rowptr[c]+k] = r ----------------
__global__ void k_fill(const int* __restrict__ row, const int* __restrict__ col,
                       const int* __restrict__ rowptr, int* __restrict__ cnt,
                       int* __restrict__ esrc) {
    int i = blockIdx.x * blockDim.x + threadIdx.x;
    if (i < NE) {
        int c = col[i];
        int pos = rowptr[c] + atomicAdd(&cnt[c], 1);
        esrc[pos] = row[i];
    }
}

// ---------------- gather: agg[c] = dinv[c]*( dinv[c]*x[c] + sum dinv[r]*x[r] ) ----
// 32-lane group per node, float4 per lane (32*16B = 512B = one row).
__global__ __launch_bounds__(256) void k_gather(const int* __restrict__ rowptr,
                                                const int* __restrict__ esrc,
                                                const float* __restrict__ x,
                                                const float* __restrict__ dinv,
                                                float* __restrict__ agg) {
    int t = threadIdx.x;
    int lane = t & 31;
    int node = blockIdx.x * 8 + (t >> 5);
    if (node >= NN) return;
    int beg = rowptr[node];
    int end = rowptr[node + 1];
    float dc = dinv[node];
    float4 xv = ((const float4*)(x + (size_t)node * DD))[lane];
    float4 acc;
    acc.x = dc * xv.x; acc.y = dc * xv.y; acc.z = dc * xv.z; acc.w = dc * xv.w;
    for (int e = beg; e < end; ++e) {
        int r = esrc[e];
        float s = dinv[r];
        float4 v = ((const float4*)(x + (size_t)r * DD))[lane];
        acc.x += s * v.x; acc.y += s * v.y; acc.z += s * v.z; acc.w += s * v.w;
    }
    acc.x *= dc; acc.y *= dc; acc.z *= dc; acc.w *= dc;
    ((float4*)(agg + (size_t)node * DD))[lane] = acc;
}

// ---------------- W -> Wt (Wt[k][c] = W[c][k]) ----------------
__global__ void k_transpose_w(const float* __restrict__ W, float* __restrict__ Wt) {
    int c = blockIdx.x;   // 128 blocks
    int k = threadIdx.x;  // 128 threads
    Wt[k * DD + c] = W[c * DD + k];
}

// ---------------- in-place GEMM + bias + relu + residual ----------------
// out (== agg buffer): out[r] = x[r] + relu(agg[r] @ Wt + b)
__global__ __launch_bounds__(256) void k_gemm(const float* __restrict__ x,
                                              const float* __restrict__ Wt,
                                              const float* __restrict__ bias,
                                              float* __restrict__ out) {
    __shared__ float wt[DD * DD];  // 64 KB
    int t = threadIdx.x;
    for (int i = t; i < DD * DD / 4; i += 256)
        ((float4*)wt)[i] = ((const float4*)Wt)[i];
    __syncthreads();

    int grp = t >> 5;             // 0..7
    int c4  = (t & 31) * 4;       // 4 consecutive output cols
    int rbase = blockIdx.x * 64 + grp * 8;

    float acc[8][4];
#pragma unroll
    for (int i = 0; i < 8; i++)
#pragma unroll
        for (int j = 0; j < 4; j++) acc[i][j] = 0.0f;

    for (int k = 0; k < DD; k += 4) {
        float4 w0 = *(const float4*)&wt[(k + 0) * DD + c4];
        float4 w1 = *(const float4*)&wt[(k + 1) * DD + c4];
        float4 w2 = *(const float4*)&wt[(k + 2) * DD + c4];
        float4 w3 = *(const float4*)&wt[(k + 3) * DD + c4];
#pragma unroll
        for (int i = 0; i < 8; i++) {
            int rr = rbase + i;
            rr = rr < NN ? rr : NN - 1;  // clamp; clamped rows' acc never written
            float4 a = *(const float4*)&out[(size_t)rr * DD + k];
            acc[i][0] += a.x * w0.x + a.y * w1.x + a.z * w2.x + a.w * w3.x;
            acc[i][1] += a.x * w0.y + a.y * w1.y + a.z * w2.y + a.w * w3.y;
            acc[i][2] += a.x * w0.z + a.y * w1.z + a.z * w2.z + a.w * w3.z;
            acc[i][3] += a.x * w0.w + a.y * w1.w + a.z * w2.w + a.w * w3.w;
        }
    }

    float4 bv = *(const float4*)&bias[c4];
#pragma unroll
    for (int i = 0; i < 8; i++) {
        int r = rbase + i;
        if (r < NN) {
            float4 xv = *(const float4*)&x[(size_t)r * DD + c4];
            float4 o;
            o.x = xv.x + fmaxf(acc[i][0] + bv.x, 0.0f);
            o.y = xv.y + fmaxf(acc[i][1] + bv.y, 0.0f);
            o.z = xv.z + fmaxf(acc[i][2] + bv.z, 0.0f);
            o.w = xv.w + fmaxf(acc[i][3] + bv.w, 0.0f);
            *(float4*)&out[(size_t)r * DD + c4] = o;
        }
    }
}

extern "C" void kernel_launch(void* const* d_in, const int* in_sizes, int n_in,
                              void* d_out, int out_size, void* d_ws, size_t ws_size,
                              hipStream_t stream) {
    const float* x   = (const float*)d_in[0];
    const int*   ei  = (const int*)d_in[1];
    const float* W   = (const float*)d_in[2];
    const float* b   = (const float*)d_in[3];
    const int* row = ei;        // edge_index[0] = source
    const int* col = ei + NE;   // edge_index[1] = target

    float* out = (float*)d_out;

    // workspace layout (bytes):
    //   deg/cnt : [0,        400000)
    //   dinv    : [400000,   800000)
    //   rowptr  : [800000,  1200004)
    //   Wt      : [1200016, 1265552)
    //   esrc    : [1265552, 7665552)   total ~7.67 MB
    char* ws = (char*)d_ws;
    int*   deg    = (int*)ws;
    float* dinv   = (float*)(ws + 400000);
    int*   rowptr = (int*)(ws + 800000);
    float* Wt     = (float*)(ws + 1200016);
    int*   esrc   = (int*)(ws + 1265552);

    hipMemsetAsync(deg, 0, NN * sizeof(int), stream);
    k_count<<<(NE + 255) / 256, 256, 0, stream>>>(col, deg);
    k_dinv<<<(NN + 255) / 256, 256, 0, stream>>>(deg, dinv);
    k_scan<<<1, 1024, 0, stream>>>(deg, rowptr);
    hipMemsetAsync(deg, 0, NN * sizeof(int), stream);  // reuse deg as fill cursor
    k_fill<<<(NE + 255) / 256, 256, 0, stream>>>(row, col, rowptr, deg, esrc);
    k_gather<<<(NN + 7) / 8, 256, 0, stream>>>(rowptr, esrc, x, dinv, out);
    k_transpose_w<<<DD, DD, 0, stream>>>(W, Wt);
    k_gemm<<<(NN + 63) / 64, 256, 0, stream>>>(x, Wt, b, out);
}

// Round 3
// 407.944 us; speedup vs baseline: 7.0098x; 1.3631x over previous
//
#include <hip/hip_runtime.h>

#define NN 100000
#define NE 1600000
#define DD 128
#define NBLK 98  // ceil(NN / 1024)

// ---------------- degree count (in-degree of col) ----------------
__global__ void k_count(const int* __restrict__ col, int* __restrict__ deg) {
    int i = blockIdx.x * blockDim.x + threadIdx.x;
    if (i < NE) atomicAdd(&deg[col[i]], 1);
}

// ---------------- dinv = (deg+1)^-0.5  (self-loop adds 1) ----------------
__global__ void k_dinv(const int* __restrict__ deg, float* __restrict__ dinv) {
    int i = blockIdx.x * blockDim.x + threadIdx.x;
    if (i < NN) dinv[i] = 1.0f / sqrtf((float)(deg[i] + 1));
}

// ---------------- scan phase A: per-block sums ----------------
__global__ __launch_bounds__(1024) void k_blocksum(const int* __restrict__ deg,
                                                   int* __restrict__ bsum) {
    __shared__ int red[1024];
    int t = threadIdx.x;
    int i = blockIdx.x * 1024 + t;
    red[t] = i < NN ? deg[i] : 0;
    __syncthreads();
    for (int off = 512; off > 0; off >>= 1) {
        if (t < off) red[t] += red[t + off];
        __syncthreads();
    }
    if (t == 0) bsum[blockIdx.x] = red[0];
}

// ---------------- scan phase B: exclusive scan of 98 block sums ----------------
__global__ void k_scanbsum(const int* __restrict__ bsum, int* __restrict__ boff) {
    __shared__ int s[128];
    int t = threadIdx.x;  // 128 threads
    s[t] = t < NBLK ? bsum[t] : 0;
    __syncthreads();
    for (int off = 1; off < 128; off <<= 1) {
        int v = t >= off ? s[t - off] : 0;
        __syncthreads();
        s[t] += v;
        __syncthreads();
    }
    if (t < NBLK) boff[t] = (t == 0) ? 0 : s[t - 1];
}

// ---------------- scan phase C: block-local exclusive scan + offset ----------------
__global__ __launch_bounds__(1024) void k_scanwrite(const int* __restrict__ deg,
                                                    const int* __restrict__ boff,
                                                    int* __restrict__ rowptr) {
    __shared__ int s[1024];
    int t = threadIdx.x;
    int i = blockIdx.x * 1024 + t;
    int v = i < NN ? deg[i] : 0;
    s[t] = v;
    __syncthreads();
    for (int off = 1; off < 1024; off <<= 1) {
        int u = t >= off ? s[t - off] : 0;
        __syncthreads();
        s[t] += u;
        __syncthreads();
    }
    if (i < NN) rowptr[i] = boff[blockIdx.x] + s[t] - v;  // exclusive
    if (i == 0) rowptr[NN] = NE;
}

// ---------------- fill CSR edge lists: esrc[rowptr[c]+k] = r ----------------
__global__ void k_fill(const int* __restrict__ row, const int* __restrict__ col,
                       const int* __restrict__ rowptr, int* __restrict__ cnt,
                       int* __restrict__ esrc) {
    int i = blockIdx.x * blockDim.x + threadIdx.x;
    if (i < NE) {
        int c = col[i];
        int pos = rowptr[c] + atomicAdd(&cnt[c], 1);
        esrc[pos] = row[i];
    }
}

// ---------------- gather: agg[c] = dinv[c]*( dinv[c]*x[c] + sum dinv[r]*x[r] ) ----
// 32-lane group per node, float4 per lane. 2-edge unroll for MLP.
__global__ __launch_bounds__(256) void k_gather(const int* __restrict__ rowptr,
                                                const int* __restrict__ esrc,
                                                const float* __restrict__ x,
                                                const float* __restrict__ dinv,
                                                float* __restrict__ agg) {
    int t = threadIdx.x;
    int lane = t & 31;
    int node = blockIdx.x * 8 + (t >> 5);
    if (node >= NN) return;
    int beg = rowptr[node];
    int end = rowptr[node + 1];
    float dc = dinv[node];
    float4 xv = ((const float4*)(x + (size_t)node * DD))[lane];
    float4 acc;
    acc.x = dc * xv.x; acc.y = dc * xv.y; acc.z = dc * xv.z; acc.w = dc * xv.w;
    int e = beg;
    for (; e + 1 < end; e += 2) {
        int r0 = esrc[e];
        int r1 = esrc[e + 1];
        float s0 = dinv[r0];
        float s1 = dinv[r1];
        float4 v0 = ((const float4*)(x + (size_t)r0 * DD))[lane];
        float4 v1 = ((const float4*)(x + (size_t)r1 * DD))[lane];
        acc.x += s0 * v0.x + s1 * v1.x;
        acc.y += s0 * v0.y + s1 * v1.y;
        acc.z += s0 * v0.z + s1 * v1.z;
        acc.w += s0 * v0.w + s1 * v1.w;
    }
    if (e < end) {
        int r = esrc[e];
        float s = dinv[r];
        float4 v = ((const float4*)(x + (size_t)r * DD))[lane];
        acc.x += s * v.x; acc.y += s * v.y; acc.z += s * v.z; acc.w += s * v.w;
    }
    acc.x *= dc; acc.y *= dc; acc.z *= dc; acc.w *= dc;
    ((float4*)(agg + (size_t)node * DD))[lane] = acc;
}

// ---------------- W -> Wt (Wt[k][c] = W[c][k]) ----------------
__global__ void k_transpose_w(const float* __restrict__ W, float* __restrict__ Wt) {
    int c = blockIdx.x;   // 128 blocks
    int k = threadIdx.x;  // 128 threads
    Wt[k * DD + c] = W[c * DD + k];
}

// ---------------- in-place GEMM + bias + relu + residual ----------------
// out (== agg buffer): out[r] = x[r] + relu(agg[r] @ Wt + b)
__global__ __launch_bounds__(256) void k_gemm(const float* __restrict__ x,
                                              const float* __restrict__ Wt,
                                              const float* __restrict__ bias,
                                              float* __restrict__ out) {
    __shared__ float wt[DD * DD];  // 64 KB
    int t = threadIdx.x;
    for (int i = t; i < DD * DD / 4; i += 256)
        ((float4*)wt)[i] = ((const float4*)Wt)[i];
    __syncthreads();

    int grp = t >> 5;             // 0..7
    int c4  = (t & 31) * 4;       // 4 consecutive output cols
    int rbase = blockIdx.x * 64 + grp * 8;

    float acc[8][4];
#pragma unroll
    for (int i = 0; i < 8; i++)
#pragma unroll
        for (int j = 0; j < 4; j++) acc[i][j] = 0.0f;

    for (int k = 0; k < DD; k += 4) {
        float4 w0 = *(const float4*)&wt[(k + 0) * DD + c4];
        float4 w1 = *(const float4*)&wt[(k + 1) * DD + c4];
        float4 w2 = *(const float4*)&wt[(k + 2) * DD + c4];
        float4 w3 = *(const float4*)&wt[(k + 3) * DD + c4];
#pragma unroll
        for (int i = 0; i < 8; i++) {
            int rr = rbase + i;
            rr = rr < NN ? rr : NN - 1;  // clamp; clamped rows' acc never written
            float4 a = *(const float4*)&out[(size_t)rr * DD + k];
            acc[i][0] += a.x * w0.x + a.y * w1.x + a.z * w2.x + a.w * w3.x;
            acc[i][1] += a.x * w0.y + a.y * w1.y + a.z * w2.y + a.w * w3.y;
            acc[i][2] += a.x * w0.z + a.y * w1.z + a.z * w2.z + a.w * w3.z;
            acc[i][3] += a.x * w0.w + a.y * w1.w + a.z * w2.w + a.w * w3.w;
        }
    }

    float4 bv = *(const float4*)&bias[c4];
#pragma unroll
    for (int i = 0; i < 8; i++) {
        int r = rbase + i;
        if (r < NN) {
            float4 xv = *(const float4*)&x[(size_t)r * DD + c4];
            float4 o;
            o.x = xv.x + fmaxf(acc[i][0] + bv.x, 0.0f);
            o.y = xv.y + fmaxf(acc[i][1] + bv.y, 0.0f);
            o.z = xv.z + fmaxf(acc[i][2] + bv.z, 0.0f);
            o.w = xv.w + fmaxf(acc[i][3] + bv.w, 0.0f);
            *(float4*)&out[(size_t)r * DD + c4] = o;
        }
    }
}

extern "C" void kernel_launch(void* const* d_in, const int* in_sizes, int n_in,
                              void* d_out, int out_size, void* d_ws, size_t ws_size,
                              hipStream_t stream) {
    const float* x   = (const float*)d_in[0];
    const int*   ei  = (const int*)d_in[1];
    const float* W   = (const float*)d_in[2];
    const float* b   = (const float*)d_in[3];
    const int* row = ei;        // edge_index[0] = source
    const int* col = ei + NE;   // edge_index[1] = target

    float* out = (float*)d_out;

    // workspace layout (bytes):
    //   deg/cnt : [0,        400000)
    //   dinv    : [400000,   800000)
    //   rowptr  : [800000,  1200004)
    //   bsum    : [1200016, 1200408)
    //   boff    : [1200416, 1200808)
    //   Wt      : [1200816, 1266352)
    //   esrc    : [1266352, 7666352)
    char* ws = (char*)d_ws;
    int*   deg    = (int*)ws;
    float* dinv   = (float*)(ws + 400000);
    int*   rowptr = (int*)(ws + 800000);
    int*   bsum   = (int*)(ws + 1200016);
    int*   boff   = (int*)(ws + 1200416);
    float* Wt     = (float*)(ws + 1200816);
    int*   esrc   = (int*)(ws + 1266352);

    hipMemsetAsync(deg, 0, NN * sizeof(int), stream);
    k_count<<<(NE + 255) / 256, 256, 0, stream>>>(col, deg);
    k_dinv<<<(NN + 255) / 256, 256, 0, stream>>>(deg, dinv);
    k_blocksum<<<NBLK, 1024, 0, stream>>>(deg, bsum);
    k_scanbsum<<<1, 128, 0, stream>>>(bsum, boff);
    k_scanwrite<<<NBLK, 1024, 0, stream>>>(deg, boff, rowptr);
    hipMemsetAsync(deg, 0, NN * sizeof(int), stream);  // reuse deg as fill cursor
    k_fill<<<(NE + 255) / 256, 256, 0, stream>>>(row, col, rowptr, deg, esrc);
    k_gather<<<(NN + 7) / 8, 256, 0, stream>>>(rowptr, esrc, x, dinv, out);
    k_transpose_w<<<DD, DD, 0, stream>>>(W, Wt);
    k_gemm<<<(NN + 63) / 64, 256, 0, stream>>>(x, Wt, b, out);
}

// Round 4
// 299.744 us; speedup vs baseline: 9.5402x; 1.3610x over previous
//
#include <hip/hip_runtime.h>

#define NN 100000
#define NE 1600000
#define DD 128
#define NBLK 98  // ceil(NN / 1024)

__device__ __forceinline__ float bf2f(unsigned short u) {
    return __uint_as_float(((unsigned)u) << 16);
}
__device__ __forceinline__ unsigned short f2bf(float f) {
    unsigned u = __float_as_uint(f);
    u += 0x7FFFu + ((u >> 16) & 1u);  // round to nearest even
    return (unsigned short)(u >> 16);
}

// ---------------- degree count + per-edge slot ----------------
__global__ void k_count_slot(const int* __restrict__ col, int* __restrict__ deg,
                             int* __restrict__ eslot) {
    int i = blockIdx.x * blockDim.x + threadIdx.x;
    if (i < NE) eslot[i] = atomicAdd(&deg[col[i]], 1);
}

// plain count (fallback path)
__global__ void k_count(const int* __restrict__ col, int* __restrict__ deg) {
    int i = blockIdx.x * blockDim.x + threadIdx.x;
    if (i < NE) atomicAdd(&deg[col[i]], 1);
}

// ---------------- per-block sums + dinv ----------------
__global__ __launch_bounds__(1024) void k_blocksum_dinv(const int* __restrict__ deg,
                                                        int* __restrict__ bsum,
                                                        float* __restrict__ dinv) {
    __shared__ int red[1024];
    int t = threadIdx.x;
    int i = blockIdx.x * 1024 + t;
    int d = i < NN ? deg[i] : 0;
    if (i < NN) dinv[i] = 1.0f / sqrtf((float)(d + 1));
    red[t] = d;
    __syncthreads();
    for (int off = 512; off > 0; off >>= 1) {
        if (t < off) red[t] += red[t + off];
        __syncthreads();
    }
    if (t == 0) bsum[blockIdx.x] = red[0];
}

// ---------------- exclusive scan of 98 block sums ----------------
__global__ void k_scanbsum(const int* __restrict__ bsum, int* __restrict__ boff) {
    __shared__ int s[128];
    int t = threadIdx.x;  // 128 threads
    s[t] = t < NBLK ? bsum[t] : 0;
    __syncthreads();
    for (int off = 1; off < 128; off <<= 1) {
        int v = t >= off ? s[t - off] : 0;
        __syncthreads();
        s[t] += v;
        __syncthreads();
    }
    if (t < NBLK) boff[t] = (t == 0) ? 0 : s[t - 1];
}

// ---------------- block-local exclusive scan + offset ----------------
__global__ __launch_bounds__(1024) void k_scanwrite(const int* __restrict__ deg,
                                                    const int* __restrict__ boff,
                                                    int* __restrict__ rowptr) {
    __shared__ int s[1024];
    int t = threadIdx.x;
    int i = blockIdx.x * 1024 + t;
    int v = i < NN ? deg[i] : 0;
    s[t] = v;
    __syncthreads();
    for (int off = 1; off < 1024; off <<= 1) {
        int u = t >= off ? s[t - off] : 0;
        __syncthreads();
        s[t] += u;
        __syncthreads();
    }
    if (i < NN) rowptr[i] = boff[blockIdx.x] + s[t] - v;  // exclusive
    if (i == 0) rowptr[NN] = NE;
}

// ---------------- xb = bf16(dinv[node] * x)  (4 elems/thread) ----------------
__global__ void k_xb(const float* __restrict__ x, const float* __restrict__ dinv,
                     unsigned short* __restrict__ xb) {
    int i = blockIdx.x * blockDim.x + threadIdx.x;  // over NN*32
    if (i < NN * 32) {
        int node = i >> 5;
        float s = dinv[node];
        float4 v = ((const float4*)x)[i];
        ushort4 o;
        o.x = f2bf(v.x * s);
        o.y = f2bf(v.y * s);
        o.z = f2bf(v.z * s);
        o.w = f2bf(v.w * s);
        ((ushort4*)xb)[i] = o;
    }
}

// ---------------- fill CSR without atomics (uses eslot) ----------------
__global__ void k_fill2(const int* __restrict__ row, const int* __restrict__ col,
                        const int* __restrict__ rowptr, const int* __restrict__ eslot,
                        int* __restrict__ esrc) {
    int i = blockIdx.x * blockDim.x + threadIdx.x;
    if (i < NE) esrc[rowptr[col[i]] + eslot[i]] = row[i];
}

// fallback fill with cursor atomics
__global__ void k_fill(const int* __restrict__ row, const int* __restrict__ col,
                       const int* __restrict__ rowptr, int* __restrict__ cnt,
                       int* __restrict__ esrc) {
    int i = blockIdx.x * blockDim.x + threadIdx.x;
    if (i < NE) {
        int c = col[i];
        int pos = rowptr[c] + atomicAdd(&cnt[c], 1);
        esrc[pos] = row[i];
    }
}

// ---------------- gather (bf16 prescaled rows) ----------------
// agg[c] = dinv[c]^2 * x[c] + dinv[c] * sum_r bf16(dinv[r]*x[r])
__global__ __launch_bounds__(256) void k_gather_bf16(const int* __restrict__ rowptr,
                                                     const int* __restrict__ esrc,
                                                     const unsigned short* __restrict__ xb,
                                                     const float* __restrict__ x,
                                                     const float* __restrict__ dinv,
                                                     float* __restrict__ agg) {
    int t = threadIdx.x;
    int lane = t & 31;
    int node = blockIdx.x * 8 + (t >> 5);
    if (node >= NN) return;
    int beg = rowptr[node];
    int end = rowptr[node + 1];
    float dc = dinv[node];
    float4 acc = make_float4(0.f, 0.f, 0.f, 0.f);
    int e = beg;
    for (; e + 3 < end; e += 4) {
        int r0 = esrc[e], r1 = esrc[e + 1], r2 = esrc[e + 2], r3 = esrc[e + 3];
        ushort4 a0 = *(const ushort4*)(xb + (size_t)r0 * DD + lane * 4);
        ushort4 a1 = *(const ushort4*)(xb + (size_t)r1 * DD + lane * 4);
        ushort4 a2 = *(const ushort4*)(xb + (size_t)r2 * DD + lane * 4);
        ushort4 a3 = *(const ushort4*)(xb + (size_t)r3 * DD + lane * 4);
        acc.x += bf2f(a0.x) + bf2f(a1.x) + bf2f(a2.x) + bf2f(a3.x);
        acc.y += bf2f(a0.y) + bf2f(a1.y) + bf2f(a2.y) + bf2f(a3.y);
        acc.z += bf2f(a0.z) + bf2f(a1.z) + bf2f(a2.z) + bf2f(a3.z);
        acc.w += bf2f(a0.w) + bf2f(a1.w) + bf2f(a2.w) + bf2f(a3.w);
    }
    for (; e < end; ++e) {
        int r = esrc[e];
        ushort4 a = *(const ushort4*)(xb + (size_t)r * DD + lane * 4);
        acc.x += bf2f(a.x); acc.y += bf2f(a.y); acc.z += bf2f(a.z); acc.w += bf2f(a.w);
    }
    float4 xv = ((const float4*)(x + (size_t)node * DD))[lane];
    float dcc = dc * dc;
    float4 o;
    o.x = dcc * xv.x + dc * acc.x;
    o.y = dcc * xv.y + dc * acc.y;
    o.z = dcc * xv.z + dc * acc.z;
    o.w = dcc * xv.w + dc * acc.w;
    ((float4*)(agg + (size_t)node * DD))[lane] = o;
}

// ---------------- gather (f32 fallback) ----------------
__global__ __launch_bounds__(256) void k_gather(const int* __restrict__ rowptr,
                                                const int* __restrict__ esrc,
                                                const float* __restrict__ x,
                                                const float* __restrict__ dinv,
                                                float* __restrict__ agg) {
    int t = threadIdx.x;
    int lane = t & 31;
    int node = blockIdx.x * 8 + (t >> 5);
    if (node >= NN) return;
    int beg = rowptr[node];
    int end = rowptr[node + 1];
    float dc = dinv[node];
    float4 xv = ((const float4*)(x + (size_t)node * DD))[lane];
    float4 acc;
    acc.x = dc * xv.x; acc.y = dc * xv.y; acc.z = dc * xv.z; acc.w = dc * xv.w;
    int e = beg;
    for (; e + 1 < end; e += 2) {
        int r0 = esrc[e];
        int r1 = esrc[e + 1];
        float s0 = dinv[r0];
        float s1 = dinv[r1];
        float4 v0 = ((const float4*)(x + (size_t)r0 * DD))[lane];
        float4 v1 = ((const float4*)(x + (size_t)r1 * DD))[lane];
        acc.x += s0 * v0.x + s1 * v1.x;
        acc.y += s0 * v0.y + s1 * v1.y;
        acc.z += s0 * v0.z + s1 * v1.z;
        acc.w += s0 * v0.w + s1 * v1.w;
    }
    if (e < end) {
        int r = esrc[e];
        float s = dinv[r];
        float4 v = ((const float4*)(x + (size_t)r * DD))[lane];
        acc.x += s * v.x; acc.y += s * v.y; acc.z += s * v.z; acc.w += s * v.w;
    }
    acc.x *= dc; acc.y *= dc; acc.z *= dc; acc.w *= dc;
    ((float4*)(agg + (size_t)node * DD))[lane] = acc;
}

// ---------------- W -> Wt (Wt[k][c] = W[c][k]) ----------------
__global__ void k_transpose_w(const float* __restrict__ W, float* __restrict__ Wt) {
    int c = blockIdx.x;   // 128 blocks
    int k = threadIdx.x;  // 128 threads
    Wt[k * DD + c] = W[c * DD + k];
}

// ---------------- in-place GEMM + bias + relu + residual ----------------
__global__ __launch_bounds__(256) void k_gemm(const float* __restrict__ x,
                                              const float* __restrict__ Wt,
                                              const float* __restrict__ bias,
                                              float* __restrict__ out) {
    __shared__ float wt[DD * DD];  // 64 KB
    int t = threadIdx.x;
    for (int i = t; i < DD * DD / 4; i += 256)
        ((float4*)wt)[i] = ((const float4*)Wt)[i];
    __syncthreads();

    int grp = t >> 5;             // 0..7
    int c4  = (t & 31) * 4;       // 4 consecutive output cols
    int rbase = blockIdx.x * 64 + grp * 8;

    float acc[8][4];
#pragma unroll
    for (int i = 0; i < 8; i++)
#pragma unroll
        for (int j = 0; j < 4; j++) acc[i][j] = 0.0f;

    for (int k = 0; k < DD; k += 4) {
        float4 w0 = *(const float4*)&wt[(k + 0) * DD + c4];
        float4 w1 = *(const float4*)&wt[(k + 1) * DD + c4];
        float4 w2 = *(const float4*)&wt[(k + 2) * DD + c4];
        float4 w3 = *(const float4*)&wt[(k + 3) * DD + c4];
#pragma unroll
        for (int i = 0; i < 8; i++) {
            int rr = rbase + i;
            rr = rr < NN ? rr : NN - 1;  // clamp; clamped rows' acc never written
            float4 a = *(const float4*)&out[(size_t)rr * DD + k];
            acc[i][0] += a.x * w0.x + a.y * w1.x + a.z * w2.x + a.w * w3.x;
            acc[i][1] += a.x * w0.y + a.y * w1.y + a.z * w2.y + a.w * w3.y;
            acc[i][2] += a.x * w0.z + a.y * w1.z + a.z * w2.z + a.w * w3.z;
            acc[i][3] += a.x * w0.w + a.y * w1.w + a.z * w2.w + a.w * w3.w;
        }
    }

    float4 bv = *(const float4*)&bias[c4];
#pragma unroll
    for (int i = 0; i < 8; i++) {
        int r = rbase + i;
        if (r < NN) {
            float4 xv = *(const float4*)&x[(size_t)r * DD + c4];
            float4 o;
            o.x = xv.x + fmaxf(acc[i][0] + bv.x, 0.0f);
            o.y = xv.y + fmaxf(acc[i][1] + bv.y, 0.0f);
            o.z = xv.z + fmaxf(acc[i][2] + bv.z, 0.0f);
            o.w = xv.w + fmaxf(acc[i][3] + bv.w, 0.0f);
            *(float4*)&out[(size_t)r * DD + c4] = o;
        }
    }
}

extern "C" void kernel_launch(void* const* d_in, const int* in_sizes, int n_in,
                              void* d_out, int out_size, void* d_ws, size_t ws_size,
                              hipStream_t stream) {
    const float* x   = (const float*)d_in[0];
    const int*   ei  = (const int*)d_in[1];
    const float* W   = (const float*)d_in[2];
    const float* b   = (const float*)d_in[3];
    const int* row = ei;        // edge_index[0] = source
    const int* col = ei + NE;   // edge_index[1] = target

    float* out = (float*)d_out;

    // workspace layout (bytes):
    //   deg/cnt : [0,        400000)
    //   dinv    : [400000,   800000)
    //   rowptr  : [800000,  1200004)
    //   bsum    : [1200016, 1200408)
    //   boff    : [1200416, 1200808)
    //   Wt      : [1200816, 1266352)
    //   esrc    : [1266352, 7666352)
    //   eslot   : [7666352, 14066352)
    //   xb      : [14066352, 39666352)
    char* ws = (char*)d_ws;
    int*   deg    = (int*)ws;
    float* dinv   = (float*)(ws + 400000);
    int*   rowptr = (int*)(ws + 800000);
    int*   bsum   = (int*)(ws + 1200016);
    int*   boff   = (int*)(ws + 1200416);
    float* Wt     = (float*)(ws + 1200816);
    int*   esrc   = (int*)(ws + 1266352);
    int*   eslot  = (int*)(ws + 7666352);
    unsigned short* xb = (unsigned short*)(ws + 14066352);

    bool big_ws = ws_size >= 39700000;  // room for eslot + xb

    hipMemsetAsync(deg, 0, NN * sizeof(int), stream);

    if (big_ws) {
        k_count_slot<<<(NE + 255) / 256, 256, 0, stream>>>(col, deg, eslot);
        k_blocksum_dinv<<<NBLK, 1024, 0, stream>>>(deg, bsum, dinv);
        k_scanbsum<<<1, 128, 0, stream>>>(bsum, boff);
        k_scanwrite<<<NBLK, 1024, 0, stream>>>(deg, boff, rowptr);
        k_xb<<<(NN * 32 + 255) / 256, 256, 0, stream>>>(x, dinv, xb);
        k_fill2<<<(NE + 255) / 256, 256, 0, stream>>>(row, col, rowptr, eslot, esrc);
        k_gather_bf16<<<(NN + 7) / 8, 256, 0, stream>>>(rowptr, esrc, xb, x, dinv, out);
    } else {
        k_count<<<(NE + 255) / 256, 256, 0, stream>>>(col, deg);
        k_blocksum_dinv<<<NBLK, 1024, 0, stream>>>(deg, bsum, dinv);
        k_scanbsum<<<1, 128, 0, stream>>>(bsum, boff);
        k_scanwrite<<<NBLK, 1024, 0, stream>>>(deg, boff, rowptr);
        hipMemsetAsync(deg, 0, NN * sizeof(int), stream);  // reuse as fill cursor
        k_fill<<<(NE + 255) / 256, 256, 0, stream>>>(row, col, rowptr, deg, esrc);
        k_gather<<<(NN + 7) / 8, 256, 0, stream>>>(rowptr, esrc, x, dinv, out);
    }

    k_transpose_w<<<DD, DD, 0, stream>>>(W, Wt);
    k_gemm<<<(NN + 63) / 64, 256, 0, stream>>>(x, Wt, b, out);
}

// Round 5
// 279.080 us; speedup vs baseline: 10.2466x; 1.0740x over previous
//
#include <hip/hip_runtime.h>

#define NN 100000
#define NE 1600000
#define DD 128
#define NBLK 98  // ceil(NN / 1024)

typedef __attribute__((ext_vector_type(8))) short bf16x8;
typedef __attribute__((ext_vector_type(4))) float f32x4;

__device__ __forceinline__ float bf2f(unsigned short u) {
    return __uint_as_float(((unsigned)u) << 16);
}
__device__ __forceinline__ unsigned short f2bf(float f) {
    unsigned u = __float_as_uint(f);
    u += 0x7FFFu + ((u >> 16) & 1u);  // round to nearest even
    return (unsigned short)(u >> 16);
}

// ---------------- degree count + per-edge slot ----------------
__global__ void k_count_slot(const int* __restrict__ col, int* __restrict__ deg,
                             int* __restrict__ eslot) {
    int i = blockIdx.x * blockDim.x + threadIdx.x;
    if (i < NE) eslot[i] = atomicAdd(&deg[col[i]], 1);
}

// plain count (fallback path)
__global__ void k_count(const int* __restrict__ col, int* __restrict__ deg) {
    int i = blockIdx.x * blockDim.x + threadIdx.x;
    if (i < NE) atomicAdd(&deg[col[i]], 1);
}

// ---------------- per-block sums + dinv ----------------
__global__ __launch_bounds__(1024) void k_blocksum_dinv(const int* __restrict__ deg,
                                                        int* __restrict__ bsum,
                                                        float* __restrict__ dinv) {
    __shared__ int red[1024];
    int t = threadIdx.x;
    int i = blockIdx.x * 1024 + t;
    int d = i < NN ? deg[i] : 0;
    if (i < NN) dinv[i] = 1.0f / sqrtf((float)(d + 1));
    red[t] = d;
    __syncthreads();
    for (int off = 512; off > 0; off >>= 1) {
        if (t < off) red[t] += red[t + off];
        __syncthreads();
    }
    if (t == 0) bsum[blockIdx.x] = red[0];
}

// ---------------- exclusive scan of 98 block sums ----------------
__global__ void k_scanbsum(const int* __restrict__ bsum, int* __restrict__ boff) {
    __shared__ int s[128];
    int t = threadIdx.x;  // 128 threads
    s[t] = t < NBLK ? bsum[t] : 0;
    __syncthreads();
    for (int off = 1; off < 128; off <<= 1) {
        int v = t >= off ? s[t - off] : 0;
        __syncthreads();
        s[t] += v;
        __syncthreads();
    }
    if (t < NBLK) boff[t] = (t == 0) ? 0 : s[t - 1];
}

// ---------------- block-local exclusive scan + offset ----------------
__global__ __launch_bounds__(1024) void k_scanwrite(const int* __restrict__ deg,
                                                    const int* __restrict__ boff,
                                                    int* __restrict__ rowptr) {
    __shared__ int s[1024];
    int t = threadIdx.x;
    int i = blockIdx.x * 1024 + t;
    int v = i < NN ? deg[i] : 0;
    s[t] = v;
    __syncthreads();
    for (int off = 1; off < 1024; off <<= 1) {
        int u = t >= off ? s[t - off] : 0;
        __syncthreads();
        s[t] += u;
        __syncthreads();
    }
    if (i < NN) rowptr[i] = boff[blockIdx.x] + s[t] - v;  // exclusive
    if (i == 0) rowptr[NN] = NE;
}

// ---------------- xb = bf16(dinv[node] * x)  (4 elems/thread) ----------------
__global__ void k_xb(const float* __restrict__ x, const float* __restrict__ dinv,
                     unsigned short* __restrict__ xb) {
    int i = blockIdx.x * blockDim.x + threadIdx.x;  // over NN*32
    if (i < NN * 32) {
        int node = i >> 5;
        float s = dinv[node];
        float4 v = ((const float4*)x)[i];
        ushort4 o;
        o.x = f2bf(v.x * s);
        o.y = f2bf(v.y * s);
        o.z = f2bf(v.z * s);
        o.w = f2bf(v.w * s);
        ((ushort4*)xb)[i] = o;
    }
}

// ---------------- fill CSR without atomics (uses eslot) ----------------
__global__ void k_fill2(const int* __restrict__ row, const int* __restrict__ col,
                        const int* __restrict__ rowptr, const int* __restrict__ eslot,
                        int* __restrict__ esrc) {
    int i = blockIdx.x * blockDim.x + threadIdx.x;
    if (i < NE) esrc[rowptr[col[i]] + eslot[i]] = row[i];
}

// fallback fill with cursor atomics
__global__ void k_fill(const int* __restrict__ row, const int* __restrict__ col,
                       const int* __restrict__ rowptr, int* __restrict__ cnt,
                       int* __restrict__ esrc) {
    int i = blockIdx.x * blockDim.x + threadIdx.x;
    if (i < NE) {
        int c = col[i];
        int pos = rowptr[c] + atomicAdd(&cnt[c], 1);
        esrc[pos] = row[i];
    }
}

// ---------------- FUSED gather + MFMA GEMM + epilogue ----------------
// Per block: 64 nodes. Phase 1: gather agg rows (bf16) -> LDS A-tile.
// Phase 2: h = A @ W^T via mfma_f32_16x16x32_bf16; out = x + relu(h + b).
// Both LDS tiles XOR-swizzled: byte ^= ((row&7)<<4) to kill ds_read_b128
// bank conflicts (row stride 256B).
__global__ __launch_bounds__(256) void k_fused(const int* __restrict__ rowptr,
                                               const int* __restrict__ esrc,
                                               const unsigned short* __restrict__ xb,
                                               const float* __restrict__ x,
                                               const float* __restrict__ dinv,
                                               const float* __restrict__ W,
                                               const float* __restrict__ bias,
                                               float* __restrict__ out) {
    __shared__ unsigned short wb[DD * DD];    // 32 KB: W rows (bf16), swizzled
    __shared__ unsigned short atile[64 * DD]; // 16 KB: agg rows (bf16), swizzled
    int t = threadIdx.x;

    // ---- stage W -> wb (f32 -> bf16), swizzled ----
#pragma unroll
    for (int it = 0; it < 8; ++it) {
        int unit = t + 256 * it;       // 2048 units x 8 cols
        int row = unit >> 4;           // output-feature row of W
        int c0 = (unit & 15) * 8;      // k-offset
        float4 v0 = *(const float4*)(W + row * DD + c0);
        float4 v1 = *(const float4*)(W + row * DD + c0 + 4);
        bf16x8 h;
        h[0] = (short)f2bf(v0.x); h[1] = (short)f2bf(v0.y);
        h[2] = (short)f2bf(v0.z); h[3] = (short)f2bf(v0.w);
        h[4] = (short)f2bf(v1.x); h[5] = (short)f2bf(v1.y);
        h[6] = (short)f2bf(v1.z); h[7] = (short)f2bf(v1.w);
        int byte = (row * 256 + c0 * 2) ^ ((row & 7) << 4);
        *(bf16x8*)((char*)wb + byte) = h;
    }

    // ---- phase 1: gather 8 nodes per 32-lane group ----
    int g = t >> 5;          // group 0..7
    int gl = t & 31;         // lane in group: covers cols gl*4..gl*4+3
    int node_base = blockIdx.x * 64;
#pragma unroll 1
    for (int i = 0; i < 8; ++i) {
        int arow = g * 8 + i;
        int node = node_base + arow;
        if (node < NN) {
            int beg = rowptr[node];
            int end = rowptr[node + 1];
            float dc = dinv[node];
            float4 acc = make_float4(0.f, 0.f, 0.f, 0.f);
            int e = beg;
            for (; e + 7 < end; e += 8) {
                ushort4 a[8];
#pragma unroll
                for (int u = 0; u < 8; ++u) {
                    int r = esrc[e + u];
                    a[u] = *(const ushort4*)(xb + (size_t)r * DD + gl * 4);
                }
#pragma unroll
                for (int u = 0; u < 8; ++u) {
                    acc.x += bf2f(a[u].x); acc.y += bf2f(a[u].y);
                    acc.z += bf2f(a[u].z); acc.w += bf2f(a[u].w);
                }
            }
            for (; e < end; ++e) {
                int r = esrc[e];
                ushort4 a = *(const ushort4*)(xb + (size_t)r * DD + gl * 4);
                acc.x += bf2f(a.x); acc.y += bf2f(a.y);
                acc.z += bf2f(a.z); acc.w += bf2f(a.w);
            }
            float4 xv = ((const float4*)(x + (size_t)node * DD))[gl];
            float dcc = dc * dc;
            ushort4 o;
            o.x = f2bf(dcc * xv.x + dc * acc.x);
            o.y = f2bf(dcc * xv.y + dc * acc.y);
            o.z = f2bf(dcc * xv.z + dc * acc.z);
            o.w = f2bf(dcc * xv.w + dc * acc.w);
            int byte = (arow * 256 + gl * 8) ^ ((arow & 7) << 4);
            *(ushort4*)((char*)atile + byte) = o;
        }
    }
    __syncthreads();

    // ---- phase 2: MFMA. wave w computes tile rows w*16..w*16+15 x all 128 cols
    int wave = t >> 6;
    int lane = t & 63;
    int lrow = lane & 15;    // row within 16-tile (A) / col within 16-tile (B,D)
    int kg = lane >> 4;      // k-group 0..3

    int arow = wave * 16 + lrow;
    bf16x8 afrag[4];
#pragma unroll
    for (int ks = 0; ks < 4; ++ks) {
        int byte = (arow * 256 + ks * 64 + kg * 16) ^ ((arow & 7) << 4);
        afrag[ks] = *(const bf16x8*)((char*)atile + byte);
    }

    f32x4 acc[8];
#pragma unroll
    for (int ct = 0; ct < 8; ++ct) acc[ct] = (f32x4)(0.f);

#pragma unroll
    for (int ct = 0; ct < 8; ++ct) {
        int wrow = ct * 16 + lrow;   // output-feature index
#pragma unroll
        for (int ks = 0; ks < 4; ++ks) {
            int byte = (wrow * 256 + ks * 64 + kg * 16) ^ ((wrow & 7) << 4);
            bf16x8 bfrag = *(const bf16x8*)((char*)wb + byte);
            acc[ct] = __builtin_amdgcn_mfma_f32_16x16x32_bf16(afrag[ks], bfrag, acc[ct], 0, 0, 0);
        }
    }

    // ---- epilogue: out[m][n] = x[m][n] + relu(h + bias[n]) ----
#pragma unroll
    for (int ct = 0; ct < 8; ++ct) {
        int n = ct * 16 + lrow;
        float bv = bias[n];
#pragma unroll
        for (int j = 0; j < 4; ++j) {
            int m = blockIdx.x * 64 + wave * 16 + kg * 4 + j;
            if (m < NN) {
                float xv = x[(size_t)m * DD + n];
                out[(size_t)m * DD + n] = xv + fmaxf(acc[ct][j] + bv, 0.f);
            }
        }
    }
}

// ---------------- f32 fallback gather ----------------
__global__ __launch_bounds__(256) void k_gather(const int* __restrict__ rowptr,
                                                const int* __restrict__ esrc,
                                                const float* __restrict__ x,
                                                const float* __restrict__ dinv,
                                                float* __restrict__ agg) {
    int t = threadIdx.x;
    int lane = t & 31;
    int node = blockIdx.x * 8 + (t >> 5);
    if (node >= NN) return;
    int beg = rowptr[node];
    int end = rowptr[node + 1];
    float dc = dinv[node];
    float4 xv = ((const float4*)(x + (size_t)node * DD))[lane];
    float4 acc;
    acc.x = dc * xv.x; acc.y = dc * xv.y; acc.z = dc * xv.z; acc.w = dc * xv.w;
    int e = beg;
    for (; e + 1 < end; e += 2) {
        int r0 = esrc[e];
        int r1 = esrc[e + 1];
        float s0 = dinv[r0];
        float s1 = dinv[r1];
        float4 v0 = ((const float4*)(x + (size_t)r0 * DD))[lane];
        float4 v1 = ((const float4*)(x + (size_t)r1 * DD))[lane];
        acc.x += s0 * v0.x + s1 * v1.x;
        acc.y += s0 * v0.y + s1 * v1.y;
        acc.z += s0 * v0.z + s1 * v1.z;
        acc.w += s0 * v0.w + s1 * v1.w;
    }
    if (e < end) {
        int r = esrc[e];
        float s = dinv[r];
        float4 v = ((const float4*)(x + (size_t)r * DD))[lane];
        acc.x += s * v.x; acc.y += s * v.y; acc.z += s * v.z; acc.w += s * v.w;
    }
    acc.x *= dc; acc.y *= dc; acc.z *= dc; acc.w *= dc;
    ((float4*)(agg + (size_t)node * DD))[lane] = acc;
}

// ---------------- fallback W -> Wt ----------------
__global__ void k_transpose_w(const float* __restrict__ W, float* __restrict__ Wt) {
    int c = blockIdx.x;
    int k = threadIdx.x;
    Wt[k * DD + c] = W[c * DD + k];
}

// ---------------- fallback vector GEMM ----------------
__global__ __launch_bounds__(256) void k_gemm(const float* __restrict__ x,
                                              const float* __restrict__ Wt,
                                              const float* __restrict__ bias,
                                              float* __restrict__ out) {
    __shared__ float wt[DD * DD];
    int t = threadIdx.x;
    for (int i = t; i < DD * DD / 4; i += 256)
        ((float4*)wt)[i] = ((const float4*)Wt)[i];
    __syncthreads();

    int grp = t >> 5;
    int c4  = (t & 31) * 4;
    int rbase = blockIdx.x * 64 + grp * 8;

    float acc[8][4];
#pragma unroll
    for (int i = 0; i < 8; i++)
#pragma unroll
        for (int j = 0; j < 4; j++) acc[i][j] = 0.0f;

    for (int k = 0; k < DD; k += 4) {
        float4 w0 = *(const float4*)&wt[(k + 0) * DD + c4];
        float4 w1 = *(const float4*)&wt[(k + 1) * DD + c4];
        float4 w2 = *(const float4*)&wt[(k + 2) * DD + c4];
        float4 w3 = *(const float4*)&wt[(k + 3) * DD + c4];
#pragma unroll
        for (int i = 0; i < 8; i++) {
            int rr = rbase + i;
            rr = rr < NN ? rr : NN - 1;
            float4 a = *(const float4*)&out[(size_t)rr * DD + k];
            acc[i][0] += a.x * w0.x + a.y * w1.x + a.z * w2.x + a.w * w3.x;
            acc[i][1] += a.x * w0.y + a.y * w1.y + a.z * w2.y + a.w * w3.y;
            acc[i][2] += a.x * w0.z + a.y * w1.z + a.z * w2.z + a.w * w3.z;
            acc[i][3] += a.x * w0.w + a.y * w1.w + a.z * w2.w + a.w * w3.w;
        }
    }

    float4 bv = *(const float4*)&bias[c4];
#pragma unroll
    for (int i = 0; i < 8; i++) {
        int r = rbase + i;
        if (r < NN) {
            float4 xv = *(const float4*)&x[(size_t)r * DD + c4];
            float4 o;
            o.x = xv.x + fmaxf(acc[i][0] + bv.x, 0.0f);
            o.y = xv.y + fmaxf(acc[i][1] + bv.y, 0.0f);
            o.z = xv.z + fmaxf(acc[i][2] + bv.z, 0.0f);
            o.w = xv.w + fmaxf(acc[i][3] + bv.w, 0.0f);
            *(float4*)&out[(size_t)r * DD + c4] = o;
        }
    }
}

extern "C" void kernel_launch(void* const* d_in, const int* in_sizes, int n_in,
                              void* d_out, int out_size, void* d_ws, size_t ws_size,
                              hipStream_t stream) {
    const float* x   = (const float*)d_in[0];
    const int*   ei  = (const int*)d_in[1];
    const float* W   = (const float*)d_in[2];
    const float* b   = (const float*)d_in[3];
    const int* row = ei;        // edge_index[0] = source
    const int* col = ei + NE;   // edge_index[1] = target

    float* out = (float*)d_out;

    // workspace layout (bytes):
    //   deg/cnt : [0,        400000)
    //   dinv    : [400000,   800000)
    //   rowptr  : [800000,  1200004)
    //   bsum    : [1200016, 1200408)
    //   boff    : [1200416, 1200808)
    //   Wt      : [1200816, 1266352)   (fallback only)
    //   esrc    : [1266352, 7666352)
    //   eslot   : [7666352, 14066352)
    //   xb      : [14066352, 39666352)
    char* ws = (char*)d_ws;
    int*   deg    = (int*)ws;
    float* dinv   = (float*)(ws + 400000);
    int*   rowptr = (int*)(ws + 800000);
    int*   bsum   = (int*)(ws + 1200016);
    int*   boff   = (int*)(ws + 1200416);
    float* Wt     = (float*)(ws + 1200816);
    int*   esrc   = (int*)(ws + 1266352);
    int*   eslot  = (int*)(ws + 7666352);
    unsigned short* xb = (unsigned short*)(ws + 14066352);

    bool big_ws = ws_size >= 39700000;

    hipMemsetAsync(deg, 0, NN * sizeof(int), stream);

    if (big_ws) {
        k_count_slot<<<(NE + 255) / 256, 256, 0, stream>>>(col, deg, eslot);
        k_blocksum_dinv<<<NBLK, 1024, 0, stream>>>(deg, bsum, dinv);
        k_scanbsum<<<1, 128, 0, stream>>>(bsum, boff);
        k_scanwrite<<<NBLK, 1024, 0, stream>>>(deg, boff, rowptr);
        k_xb<<<(NN * 32 + 255) / 256, 256, 0, stream>>>(x, dinv, xb);
        k_fill2<<<(NE + 255) / 256, 256, 0, stream>>>(row, col, rowptr, eslot, esrc);
        k_fused<<<(NN + 63) / 64, 256, 0, stream>>>(rowptr, esrc, xb, x, dinv, W, b, out);
    } else {
        k_count<<<(NE + 255) / 256, 256, 0, stream>>>(col, deg);
        k_blocksum_dinv<<<NBLK, 1024, 0, stream>>>(deg, bsum, dinv);
        k_scanbsum<<<1, 128, 0, stream>>>(bsum, boff);
        k_scanwrite<<<NBLK, 1024, 0, stream>>>(deg, boff, rowptr);
        hipMemsetAsync(deg, 0, NN * sizeof(int), stream);
        k_fill<<<(NE + 255) / 256, 256, 0, stream>>>(row, col, rowptr, deg, esrc);
        k_gather<<<(NN + 7) / 8, 256, 0, stream>>>(rowptr, esrc, x, dinv, out);
        k_transpose_w<<<DD, DD, 0, stream>>>(W, Wt);
        k_gemm<<<(NN + 63) / 64, 256, 0, stream>>>(x, Wt, b, out);
    }
}

// Round 6
// 235.841 us; speedup vs baseline: 12.1252x; 1.1833x over previous
//
#include <hip/hip_runtime.h>

#define NN 100000
#define NE 1600000
#define DD 128
#define NBLK 98  // ceil(NN / 1024)

typedef __attribute__((ext_vector_type(8))) short bf16x8;
typedef __attribute__((ext_vector_type(4))) float f32x4;

__device__ __forceinline__ float bf2f(unsigned short u) {
    return __uint_as_float(((unsigned)u) << 16);
}
__device__ __forceinline__ unsigned short f2bf(float f) {
    unsigned u = __float_as_uint(f);
    u += 0x7FFFu + ((u >> 16) & 1u);  // round to nearest even
    return (unsigned short)(u >> 16);
}

// ---------------- degree count + per-edge slot ----------------
__global__ void k_count_slot(const int* __restrict__ col, int* __restrict__ deg,
                             int* __restrict__ eslot) {
    int i = blockIdx.x * blockDim.x + threadIdx.x;
    if (i < NE) eslot[i] = atomicAdd(&deg[col[i]], 1);
}

// plain count (fallback path)
__global__ void k_count(const int* __restrict__ col, int* __restrict__ deg) {
    int i = blockIdx.x * blockDim.x + threadIdx.x;
    if (i < NE) atomicAdd(&deg[col[i]], 1);
}

// ---------------- per-block sums + dinv ----------------
__global__ __launch_bounds__(1024) void k_blocksum_dinv(const int* __restrict__ deg,
                                                        int* __restrict__ bsum,
                                                        float* __restrict__ dinv) {
    __shared__ int red[1024];
    int t = threadIdx.x;
    int i = blockIdx.x * 1024 + t;
    int d = i < NN ? deg[i] : 0;
    if (i < NN) dinv[i] = 1.0f / sqrtf((float)(d + 1));
    red[t] = d;
    __syncthreads();
    for (int off = 512; off > 0; off >>= 1) {
        if (t < off) red[t] += red[t + off];
        __syncthreads();
    }
    if (t == 0) bsum[blockIdx.x] = red[0];
}

// ---------------- exclusive scan of 98 block sums ----------------
__global__ void k_scanbsum(const int* __restrict__ bsum, int* __restrict__ boff) {
    __shared__ int s[128];
    int t = threadIdx.x;  // 128 threads
    s[t] = t < NBLK ? bsum[t] : 0;
    __syncthreads();
    for (int off = 1; off < 128; off <<= 1) {
        int v = t >= off ? s[t - off] : 0;
        __syncthreads();
        s[t] += v;
        __syncthreads();
    }
    if (t < NBLK) boff[t] = (t == 0) ? 0 : s[t - 1];
}

// ---------------- block-local exclusive scan + offset ----------------
__global__ __launch_bounds__(1024) void k_scanwrite(const int* __restrict__ deg,
                                                    const int* __restrict__ boff,
                                                    int* __restrict__ rowptr) {
    __shared__ int s[1024];
    int t = threadIdx.x;
    int i = blockIdx.x * 1024 + t;
    int v = i < NN ? deg[i] : 0;
    s[t] = v;
    __syncthreads();
    for (int off = 1; off < 1024; off <<= 1) {
        int u = t >= off ? s[t - off] : 0;
        __syncthreads();
        s[t] += u;
        __syncthreads();
    }
    if (i < NN) rowptr[i] = boff[blockIdx.x] + s[t] - v;  // exclusive
    if (i == 0) rowptr[NN] = NE;
}

// ---------------- xb = bf16(dinv[node] * x)  (4 elems/thread) ----------------
__global__ void k_xb(const float* __restrict__ x, const float* __restrict__ dinv,
                     unsigned short* __restrict__ xb) {
    int i = blockIdx.x * blockDim.x + threadIdx.x;  // over NN*32
    if (i < NN * 32) {
        int node = i >> 5;
        float s = dinv[node];
        float4 v = ((const float4*)x)[i];
        ushort4 o;
        o.x = f2bf(v.x * s);
        o.y = f2bf(v.y * s);
        o.z = f2bf(v.z * s);
        o.w = f2bf(v.w * s);
        ((ushort4*)xb)[i] = o;
    }
}

// ---------------- fill CSR without atomics (uses eslot) ----------------
__global__ void k_fill2(const int* __restrict__ row, const int* __restrict__ col,
                        const int* __restrict__ rowptr, const int* __restrict__ eslot,
                        int* __restrict__ esrc) {
    int i = blockIdx.x * blockDim.x + threadIdx.x;
    if (i < NE) esrc[rowptr[col[i]] + eslot[i]] = row[i];
}

// fallback fill with cursor atomics
__global__ void k_fill(const int* __restrict__ row, const int* __restrict__ col,
                       const int* __restrict__ rowptr, int* __restrict__ cnt,
                       int* __restrict__ esrc) {
    int i = blockIdx.x * blockDim.x + threadIdx.x;
    if (i < NE) {
        int c = col[i];
        int pos = rowptr[c] + atomicAdd(&cnt[c], 1);
        esrc[pos] = row[i];
    }
}

// ---------------- W -> pre-swizzled bf16 (global, 32 KB) ----------------
__global__ void k_wb(const float* __restrict__ W, unsigned short* __restrict__ wbs) {
    int unit = blockIdx.x * 256 + threadIdx.x;  // 2048 units x 8 elems
    int row = unit >> 4;                        // output-feature row
    int c0 = (unit & 15) * 8;                   // k offset
    float4 v0 = *(const float4*)(W + row * DD + c0);
    float4 v1 = *(const float4*)(W + row * DD + c0 + 4);
    bf16x8 h;
    h[0] = (short)f2bf(v0.x); h[1] = (short)f2bf(v0.y);
    h[2] = (short)f2bf(v0.z); h[3] = (short)f2bf(v0.w);
    h[4] = (short)f2bf(v1.x); h[5] = (short)f2bf(v1.y);
    h[6] = (short)f2bf(v1.z); h[7] = (short)f2bf(v1.w);
    int byte = (row * 256 + c0 * 2) ^ ((row & 7) << 4);  // XOR-swizzle
    *(bf16x8*)((char*)wbs + byte) = h;
}

// ---------------- gather (bf16), writes aggb packed into out rows ----------------
// aggb row m = bytes [512m+256, 512m+512) of out; 256 B bf16 row.
__global__ __launch_bounds__(256) void k_gather_bf16(const int* __restrict__ rowptr,
                                                     const int* __restrict__ esrc,
                                                     const unsigned short* __restrict__ xb,
                                                     const float* __restrict__ x,
                                                     const float* __restrict__ dinv,
                                                     char* __restrict__ aggb) {
    int t = threadIdx.x;
    int gl = t & 31;
    int node = blockIdx.x * 8 + (t >> 5);
    if (node >= NN) return;
    int beg = rowptr[node];
    int end = rowptr[node + 1];
    float dc = dinv[node];
    float4 acc = make_float4(0.f, 0.f, 0.f, 0.f);
    int e = beg;
    for (; e + 7 < end; e += 8) {
        ushort4 a[8];
#pragma unroll
        for (int u = 0; u < 8; ++u) {
            int r = esrc[e + u];
            a[u] = *(const ushort4*)(xb + (size_t)r * DD + gl * 4);
        }
#pragma unroll
        for (int u = 0; u < 8; ++u) {
            acc.x += bf2f(a[u].x); acc.y += bf2f(a[u].y);
            acc.z += bf2f(a[u].z); acc.w += bf2f(a[u].w);
        }
    }
    for (; e < end; ++e) {
        int r = esrc[e];
        ushort4 a = *(const ushort4*)(xb + (size_t)r * DD + gl * 4);
        acc.x += bf2f(a.x); acc.y += bf2f(a.y); acc.z += bf2f(a.z); acc.w += bf2f(a.w);
    }
    float4 xv = ((const float4*)(x + (size_t)node * DD))[gl];
    float dcc = dc * dc;
    ushort4 o;
    o.x = f2bf(dcc * xv.x + dc * acc.x);
    o.y = f2bf(dcc * xv.y + dc * acc.y);
    o.z = f2bf(dcc * xv.z + dc * acc.z);
    o.w = f2bf(dcc * xv.w + dc * acc.w);
    *(ushort4*)(aggb + (size_t)node * 512 + 256 + gl * 8) = o;
}

// ---------------- MFMA GEMM: out = x + relu(aggb @ W^T + b) ----------------
// A-frags read straight from aggb (inside out); safe in-place: each wave reads
// only its own 16 rows, and all afrag loads are consumed by MFMAs before the
// epilogue stores overwrite those bytes.
__global__ __launch_bounds__(256) void k_mgemm(const unsigned short* __restrict__ wbs,
                                               const float* __restrict__ x,
                                               const float* __restrict__ bias,
                                               float* out) {
    __shared__ unsigned short wb[DD * DD];  // 32 KB, already swizzled
    int t = threadIdx.x;
#pragma unroll
    for (int i = 0; i < 8; ++i)
        ((float4*)wb)[t + 256 * i] = ((const float4*)wbs)[t + 256 * i];
    __syncthreads();

    int wave = t >> 6;
    int lane = t & 63;
    int lrow = lane & 15;   // A row within 16-tile / D col
    int kg = lane >> 4;     // k-group 0..3

    int arow = blockIdx.x * 64 + wave * 16 + lrow;
    int arc = arow < NN ? arow : NN - 1;  // clamped rows' outputs never written
    bf16x8 afrag[4];
#pragma unroll
    for (int ks = 0; ks < 4; ++ks)
        afrag[ks] = *(const bf16x8*)((const char*)out + (size_t)arc * 512 + 256 + ks * 64 + kg * 16);

    f32x4 acc[8];
#pragma unroll
    for (int ct = 0; ct < 8; ++ct) acc[ct] = (f32x4)(0.f);

#pragma unroll
    for (int ct = 0; ct < 8; ++ct) {
        int wrow = ct * 16 + lrow;  // output-feature index
#pragma unroll
        for (int ks = 0; ks < 4; ++ks) {
            int byte = (wrow * 256 + ks * 64 + kg * 16) ^ ((wrow & 7) << 4);
            bf16x8 bfrag = *(const bf16x8*)((char*)wb + byte);
            acc[ct] = __builtin_amdgcn_mfma_f32_16x16x32_bf16(afrag[ks], bfrag, acc[ct], 0, 0, 0);
        }
    }

#pragma unroll
    for (int ct = 0; ct < 8; ++ct) {
        int n = ct * 16 + lrow;
        float bv = bias[n];
#pragma unroll
        for (int j = 0; j < 4; ++j) {
            int m = blockIdx.x * 64 + wave * 16 + kg * 4 + j;
            if (m < NN) {
                float xv = x[(size_t)m * DD + n];
                out[(size_t)m * DD + n] = xv + fmaxf(acc[ct][j] + bv, 0.f);
            }
        }
    }
}

// ---------------- f32 fallback gather ----------------
__global__ __launch_bounds__(256) void k_gather(const int* __restrict__ rowptr,
                                                const int* __restrict__ esrc,
                                                const float* __restrict__ x,
                                                const float* __restrict__ dinv,
                                                float* __restrict__ agg) {
    int t = threadIdx.x;
    int lane = t & 31;
    int node = blockIdx.x * 8 + (t >> 5);
    if (node >= NN) return;
    int beg = rowptr[node];
    int end = rowptr[node + 1];
    float dc = dinv[node];
    float4 xv = ((const float4*)(x + (size_t)node * DD))[lane];
    float4 acc;
    acc.x = dc * xv.x; acc.y = dc * xv.y; acc.z = dc * xv.z; acc.w = dc * xv.w;
    int e = beg;
    for (; e + 1 < end; e += 2) {
        int r0 = esrc[e];
        int r1 = esrc[e + 1];
        float s0 = dinv[r0];
        float s1 = dinv[r1];
        float4 v0 = ((const float4*)(x + (size_t)r0 * DD))[lane];
        float4 v1 = ((const float4*)(x + (size_t)r1 * DD))[lane];
        acc.x += s0 * v0.x + s1 * v1.x;
        acc.y += s0 * v0.y + s1 * v1.y;
        acc.z += s0 * v0.z + s1 * v1.z;
        acc.w += s0 * v0.w + s1 * v1.w;
    }
    if (e < end) {
        int r = esrc[e];
        float s = dinv[r];
        float4 v = ((const float4*)(x + (size_t)r * DD))[lane];
        acc.x += s * v.x; acc.y += s * v.y; acc.z += s * v.z; acc.w += s * v.w;
    }
    acc.x *= dc; acc.y *= dc; acc.z *= dc; acc.w *= dc;
    ((float4*)(agg + (size_t)node * DD))[lane] = acc;
}

// ---------------- fallback W -> Wt ----------------
__global__ void k_transpose_w(const float* __restrict__ W, float* __restrict__ Wt) {
    int c = blockIdx.x;
    int k = threadIdx.x;
    Wt[k * DD + c] = W[c * DD + k];
}

// ---------------- fallback vector GEMM ----------------
__global__ __launch_bounds__(256) void k_gemm(const float* __restrict__ x,
                                              const float* __restrict__ Wt,
                                              const float* __restrict__ bias,
                                              float* __restrict__ out) {
    __shared__ float wt[DD * DD];
    int t = threadIdx.x;
    for (int i = t; i < DD * DD / 4; i += 256)
        ((float4*)wt)[i] = ((const float4*)Wt)[i];
    __syncthreads();

    int grp = t >> 5;
    int c4  = (t & 31) * 4;
    int rbase = blockIdx.x * 64 + grp * 8;

    float acc[8][4];
#pragma unroll
    for (int i = 0; i < 8; i++)
#pragma unroll
        for (int j = 0; j < 4; j++) acc[i][j] = 0.0f;

    for (int k = 0; k < DD; k += 4) {
        float4 w0 = *(const float4*)&wt[(k + 0) * DD + c4];
        float4 w1 = *(const float4*)&wt[(k + 1) * DD + c4];
        float4 w2 = *(const float4*)&wt[(k + 2) * DD + c4];
        float4 w3 = *(const float4*)&wt[(k + 3) * DD + c4];
#pragma unroll
        for (int i = 0; i < 8; i++) {
            int rr = rbase + i;
            rr = rr < NN ? rr : NN - 1;
            float4 a = *(const float4*)&out[(size_t)rr * DD + k];
            acc[i][0] += a.x * w0.x + a.y * w1.x + a.z * w2.x + a.w * w3.x;
            acc[i][1] += a.x * w0.y + a.y * w1.y + a.z * w2.y + a.w * w3.y;
            acc[i][2] += a.x * w0.z + a.y * w1.z + a.z * w2.z + a.w * w3.z;
            acc[i][3] += a.x * w0.w + a.y * w1.w + a.z * w2.w + a.w * w3.w;
        }
    }

    float4 bv = *(const float4*)&bias[c4];
#pragma unroll
    for (int i = 0; i < 8; i++) {
        int r = rbase + i;
        if (r < NN) {
            float4 xv = *(const float4*)&x[(size_t)r * DD + c4];
            float4 o;
            o.x = xv.x + fmaxf(acc[i][0] + bv.x, 0.0f);
            o.y = xv.y + fmaxf(acc[i][1] + bv.y, 0.0f);
            o.z = xv.z + fmaxf(acc[i][2] + bv.z, 0.0f);
            o.w = xv.w + fmaxf(acc[i][3] + bv.w, 0.0f);
            *(float4*)&out[(size_t)r * DD + c4] = o;
        }
    }
}

extern "C" void kernel_launch(void* const* d_in, const int* in_sizes, int n_in,
                              void* d_out, int out_size, void* d_ws, size_t ws_size,
                              hipStream_t stream) {
    const float* x   = (const float*)d_in[0];
    const int*   ei  = (const int*)d_in[1];
    const float* W   = (const float*)d_in[2];
    const float* b   = (const float*)d_in[3];
    const int* row = ei;        // edge_index[0] = source
    const int* col = ei + NE;   // edge_index[1] = target

    float* out = (float*)d_out;

    // workspace layout (bytes):
    //   deg/cnt : [0,        400000)
    //   dinv    : [400000,   800000)
    //   rowptr  : [800000,  1200004)
    //   bsum    : [1200016, 1200408)
    //   boff    : [1200416, 1200808)
    //   wbs/Wt  : [1200816, 1266352)   (swizzled bf16 W / fallback Wt)
    //   esrc    : [1266352, 7666352)
    //   eslot   : [7666352, 14066352)
    //   xb      : [14066352, 39666352)
    char* ws = (char*)d_ws;
    int*   deg    = (int*)ws;
    float* dinv   = (float*)(ws + 400000);
    int*   rowptr = (int*)(ws + 800000);
    int*   bsum   = (int*)(ws + 1200016);
    int*   boff   = (int*)(ws + 1200416);
    unsigned short* wbs = (unsigned short*)(ws + 1200816);
    float* Wt     = (float*)(ws + 1200816);
    int*   esrc   = (int*)(ws + 1266352);
    int*   eslot  = (int*)(ws + 7666352);
    unsigned short* xb = (unsigned short*)(ws + 14066352);

    bool big_ws = ws_size >= 39700000;

    hipMemsetAsync(deg, 0, NN * sizeof(int), stream);

    if (big_ws) {
        k_count_slot<<<(NE + 255) / 256, 256, 0, stream>>>(col, deg, eslot);
        k_blocksum_dinv<<<NBLK, 1024, 0, stream>>>(deg, bsum, dinv);
        k_scanbsum<<<1, 128, 0, stream>>>(bsum, boff);
        k_scanwrite<<<NBLK, 1024, 0, stream>>>(deg, boff, rowptr);
        k_xb<<<(NN * 32 + 255) / 256, 256, 0, stream>>>(x, dinv, xb);
        k_fill2<<<(NE + 255) / 256, 256, 0, stream>>>(row, col, rowptr, eslot, esrc);
        k_wb<<<8, 256, 0, stream>>>(W, wbs);
        k_gather_bf16<<<(NN + 7) / 8, 256, 0, stream>>>(rowptr, esrc, xb, x, dinv, (char*)out);
        k_mgemm<<<(NN + 63) / 64, 256, 0, stream>>>(wbs, x, b, out);
    } else {
        k_count<<<(NE + 255) / 256, 256, 0, stream>>>(col, deg);
        k_blocksum_dinv<<<NBLK, 1024, 0, stream>>>(deg, bsum, dinv);
        k_scanbsum<<<1, 128, 0, stream>>>(bsum, boff);
        k_scanwrite<<<NBLK, 1024, 0, stream>>>(deg, boff, rowptr);
        hipMemsetAsync(deg, 0, NN * sizeof(int), stream);
        k_fill<<<(NE + 255) / 256, 256, 0, stream>>>(row, col, rowptr, deg, esrc);
        k_gather<<<(NN + 7) / 8, 256, 0, stream>>>(rowptr, esrc, x, dinv, out);
        k_transpose_w<<<DD, DD, 0, stream>>>(W, Wt);
        k_gemm<<<(NN + 63) / 64, 256, 0, stream>>>(x, Wt, b, out);
    }
}

// Round 7
// 222.113 us; speedup vs baseline: 12.8746x; 1.0618x over previous
//
#include <hip/hip_runtime.h>

#define NN 100000
#define NE 1600000
#define DD 128
#define NBLK 98  // ceil(NN / 1024)

typedef __attribute__((ext_vector_type(8))) short bf16x8;
typedef __attribute__((ext_vector_type(4))) float f32x4;

__device__ __forceinline__ float bf2f(unsigned short u) {
    return __uint_as_float(((unsigned)u) << 16);
}
__device__ __forceinline__ unsigned short f2bf(float f) {
    unsigned u = __float_as_uint(f);
    u += 0x7FFFu + ((u >> 16) & 1u);  // round to nearest even
    return (unsigned short)(u >> 16);
}

// ---------------- degree count + per-edge slot ----------------
__global__ void k_count_slot(const int* __restrict__ col, int* __restrict__ deg,
                             int* __restrict__ eslot) {
    int i = blockIdx.x * blockDim.x + threadIdx.x;
    if (i < NE) eslot[i] = atomicAdd(&deg[col[i]], 1);
}

// plain count (fallback path)
__global__ void k_count(const int* __restrict__ col, int* __restrict__ deg) {
    int i = blockIdx.x * blockDim.x + threadIdx.x;
    if (i < NE) atomicAdd(&deg[col[i]], 1);
}

// ---------------- per-block sums + dinv ----------------
__global__ __launch_bounds__(1024) void k_blocksum_dinv(const int* __restrict__ deg,
                                                        int* __restrict__ bsum,
                                                        float* __restrict__ dinv) {
    __shared__ int red[1024];
    int t = threadIdx.x;
    int i = blockIdx.x * 1024 + t;
    int d = i < NN ? deg[i] : 0;
    if (i < NN) dinv[i] = 1.0f / sqrtf((float)(d + 1));
    red[t] = d;
    __syncthreads();
    for (int off = 512; off > 0; off >>= 1) {
        if (t < off) red[t] += red[t + off];
        __syncthreads();
    }
    if (t == 0) bsum[blockIdx.x] = red[0];
}

// ---------------- scan: every block redundantly scans bsum, then local scan ----
__global__ __launch_bounds__(1024) void k_scanwrite2(const int* __restrict__ deg,
                                                     const int* __restrict__ bsum,
                                                     int* __restrict__ rowptr) {
    __shared__ int sb[128];
    __shared__ int s[1024];
    int t = threadIdx.x;
    if (t < 128) sb[t] = t < NBLK ? bsum[t] : 0;
    __syncthreads();
    for (int off = 1; off < 128; off <<= 1) {
        int v = 0;
        if (t < 128 && t >= off) v = sb[t - off];
        __syncthreads();
        if (t < 128) sb[t] += v;
        __syncthreads();
    }
    int boff = blockIdx.x == 0 ? 0 : sb[blockIdx.x - 1];
    int i = blockIdx.x * 1024 + t;
    int v = i < NN ? deg[i] : 0;
    s[t] = v;
    __syncthreads();
    for (int off = 1; off < 1024; off <<= 1) {
        int u = t >= off ? s[t - off] : 0;
        __syncthreads();
        s[t] += u;
        __syncthreads();
    }
    if (i < NN) rowptr[i] = boff + s[t] - v;  // exclusive
    if (i == 0) rowptr[NN] = NE;
}

// fallback scan kernels
__global__ void k_scanbsum(const int* __restrict__ bsum, int* __restrict__ boff) {
    __shared__ int s[128];
    int t = threadIdx.x;
    s[t] = t < NBLK ? bsum[t] : 0;
    __syncthreads();
    for (int off = 1; off < 128; off <<= 1) {
        int v = t >= off ? s[t - off] : 0;
        __syncthreads();
        s[t] += v;
        __syncthreads();
    }
    if (t < NBLK) boff[t] = (t == 0) ? 0 : s[t - 1];
}
__global__ __launch_bounds__(1024) void k_scanwrite(const int* __restrict__ deg,
                                                    const int* __restrict__ boff,
                                                    int* __restrict__ rowptr) {
    __shared__ int s[1024];
    int t = threadIdx.x;
    int i = blockIdx.x * 1024 + t;
    int v = i < NN ? deg[i] : 0;
    s[t] = v;
    __syncthreads();
    for (int off = 1; off < 1024; off <<= 1) {
        int u = t >= off ? s[t - off] : 0;
        __syncthreads();
        s[t] += u;
        __syncthreads();
    }
    if (i < NN) rowptr[i] = boff[blockIdx.x] + s[t] - v;
    if (i == 0) rowptr[NN] = NE;
}

// ---------------- fill CSR without atomics (uses eslot) ----------------
__global__ void k_fill2(const int* __restrict__ row, const int* __restrict__ col,
                        const int* __restrict__ rowptr, const int* __restrict__ eslot,
                        int* __restrict__ esrc) {
    int i = blockIdx.x * blockDim.x + threadIdx.x;
    if (i < NE) esrc[rowptr[col[i]] + eslot[i]] = row[i];
}

// fallback fill with cursor atomics
__global__ void k_fill(const int* __restrict__ row, const int* __restrict__ col,
                       const int* __restrict__ rowptr, int* __restrict__ cnt,
                       int* __restrict__ esrc) {
    int i = blockIdx.x * blockDim.x + threadIdx.x;
    if (i < NE) {
        int c = col[i];
        int pos = rowptr[c] + atomicAdd(&cnt[c], 1);
        esrc[pos] = row[i];
    }
}

// ---------------- W -> pre-swizzled bf16 (global, 32 KB) ----------------
__global__ void k_wb(const float* __restrict__ W, unsigned short* __restrict__ wbs) {
    int unit = blockIdx.x * 256 + threadIdx.x;  // 2048 units x 8 elems
    int row = unit >> 4;                        // output-feature row
    int c0 = (unit & 15) * 8;                   // k offset
    float4 v0 = *(const float4*)(W + row * DD + c0);
    float4 v1 = *(const float4*)(W + row * DD + c0 + 4);
    bf16x8 h;
    h[0] = (short)f2bf(v0.x); h[1] = (short)f2bf(v0.y);
    h[2] = (short)f2bf(v0.z); h[3] = (short)f2bf(v0.w);
    h[4] = (short)f2bf(v1.x); h[5] = (short)f2bf(v1.y);
    h[6] = (short)f2bf(v1.z); h[7] = (short)f2bf(v1.w);
    int byte = (row * 256 + c0 * 2) ^ ((row & 7) << 4);  // XOR-swizzle
    *(bf16x8*)((char*)wbs + byte) = h;
}

// ---------------- MFMA GEMM: yb[m] = bf16( dinv[m] * (x[m] @ W^T) ) ----------------
// Same verified MFMA structure as R5's k_mgemm; A-frags converted from global
// f32 x on the fly, D prescaled by dinv and stored bf16.
__global__ __launch_bounds__(256) void k_ygemm(const float* __restrict__ x,
                                               const unsigned short* __restrict__ wbs,
                                               const float* __restrict__ dinv,
                                               unsigned short* __restrict__ yb) {
    __shared__ unsigned short wb[DD * DD];  // 32 KB, already swizzled
    int t = threadIdx.x;
#pragma unroll
    for (int i = 0; i < 8; ++i)
        ((float4*)wb)[t + 256 * i] = ((const float4*)wbs)[t + 256 * i];
    __syncthreads();

    int wave = t >> 6;
    int lane = t & 63;
    int lrow = lane & 15;   // A row within 16-tile / D col (feature n)
    int kg = lane >> 4;     // k-group 0..3

    int arow = blockIdx.x * 64 + wave * 16 + lrow;
    int arc = arow < NN ? arow : NN - 1;  // clamped rows' outputs never written
    bf16x8 afrag[4];
#pragma unroll
    for (int ks = 0; ks < 4; ++ks) {
        const float* src = x + (size_t)arc * DD + ks * 32 + kg * 8;
        float4 v0 = *(const float4*)src;
        float4 v1 = *(const float4*)(src + 4);
        bf16x8 h;
        h[0] = (short)f2bf(v0.x); h[1] = (short)f2bf(v0.y);
        h[2] = (short)f2bf(v0.z); h[3] = (short)f2bf(v0.w);
        h[4] = (short)f2bf(v1.x); h[5] = (short)f2bf(v1.y);
        h[6] = (short)f2bf(v1.z); h[7] = (short)f2bf(v1.w);
        afrag[ks] = h;
    }

    f32x4 acc[8];
#pragma unroll
    for (int ct = 0; ct < 8; ++ct) acc[ct] = (f32x4)(0.f);

#pragma unroll
    for (int ct = 0; ct < 8; ++ct) {
        int wrow = ct * 16 + lrow;  // output-feature index
#pragma unroll
        for (int ks = 0; ks < 4; ++ks) {
            int byte = (wrow * 256 + ks * 64 + kg * 16) ^ ((wrow & 7) << 4);
            bf16x8 bfrag = *(const bf16x8*)((char*)wb + byte);
            acc[ct] = __builtin_amdgcn_mfma_f32_16x16x32_bf16(afrag[ks], bfrag, acc[ct], 0, 0, 0);
        }
    }

    float dv[4];
#pragma unroll
    for (int j = 0; j < 4; ++j) {
        int m = blockIdx.x * 64 + wave * 16 + kg * 4 + j;
        dv[j] = m < NN ? dinv[m] : 0.f;
    }
#pragma unroll
    for (int ct = 0; ct < 8; ++ct) {
        int n = ct * 16 + lrow;
#pragma unroll
        for (int j = 0; j < 4; ++j) {
            int m = blockIdx.x * 64 + wave * 16 + kg * 4 + j;
            if (m < NN) yb[(size_t)m * DD + n] = f2bf(dv[j] * acc[ct][j]);
        }
    }
}

// ---------------- fused gather + epilogue ----------------
// out[c] = x[c] + relu( dinv[c] * (yb[c] + sum_{r in N(c)} yb[r]) + b )
__global__ __launch_bounds__(256) void k_gather_fused(const int* __restrict__ rowptr,
                                                      const int* __restrict__ esrc,
                                                      const unsigned short* __restrict__ yb,
                                                      const float* __restrict__ x,
                                                      const float* __restrict__ dinv,
                                                      const float* __restrict__ bias,
                                                      float* __restrict__ out) {
    int t = threadIdx.x;
    int gl = t & 31;
    int node = blockIdx.x * 8 + (t >> 5);
    if (node >= NN) return;
    int beg = rowptr[node];
    int end = rowptr[node + 1];
    float dc = dinv[node];

    ushort4 sv = *(const ushort4*)(yb + (size_t)node * DD + gl * 4);  // self-loop
    float4 acc;
    acc.x = bf2f(sv.x); acc.y = bf2f(sv.y); acc.z = bf2f(sv.z); acc.w = bf2f(sv.w);

    int e = beg;
    for (; e + 7 < end; e += 8) {
        ushort4 a[8];
#pragma unroll
        for (int u = 0; u < 8; ++u) {
            int r = esrc[e + u];
            a[u] = *(const ushort4*)(yb + (size_t)r * DD + gl * 4);
        }
#pragma unroll
        for (int u = 0; u < 8; ++u) {
            acc.x += bf2f(a[u].x); acc.y += bf2f(a[u].y);
            acc.z += bf2f(a[u].z); acc.w += bf2f(a[u].w);
        }
    }
    for (; e < end; ++e) {
        int r = esrc[e];
        ushort4 a = *(const ushort4*)(yb + (size_t)r * DD + gl * 4);
        acc.x += bf2f(a.x); acc.y += bf2f(a.y); acc.z += bf2f(a.z); acc.w += bf2f(a.w);
    }

    float4 bv = *(const float4*)(bias + gl * 4);
    float4 xv = ((const float4*)(x + (size_t)node * DD))[gl];
    float4 o;
    o.x = xv.x + fmaxf(dc * acc.x + bv.x, 0.f);
    o.y = xv.y + fmaxf(dc * acc.y + bv.y, 0.f);
    o.z = xv.z + fmaxf(dc * acc.z + bv.z, 0.f);
    o.w = xv.w + fmaxf(dc * acc.w + bv.w, 0.f);
    ((float4*)(out + (size_t)node * DD))[gl] = o;
}

// ---------------- f32 fallback gather ----------------
__global__ __launch_bounds__(256) void k_gather(const int* __restrict__ rowptr,
                                                const int* __restrict__ esrc,
                                                const float* __restrict__ x,
                                                const float* __restrict__ dinv,
                                                float* __restrict__ agg) {
    int t = threadIdx.x;
    int lane = t & 31;
    int node = blockIdx.x * 8 + (t >> 5);
    if (node >= NN) return;
    int beg = rowptr[node];
    int end = rowptr[node + 1];
    float dc = dinv[node];
    float4 xv = ((const float4*)(x + (size_t)node * DD))[lane];
    float4 acc;
    acc.x = dc * xv.x; acc.y = dc * xv.y; acc.z = dc * xv.z; acc.w = dc * xv.w;
    int e = beg;
    for (; e + 1 < end; e += 2) {
        int r0 = esrc[e];
        int r1 = esrc[e + 1];
        float s0 = dinv[r0];
        float s1 = dinv[r1];
        float4 v0 = ((const float4*)(x + (size_t)r0 * DD))[lane];
        float4 v1 = ((const float4*)(x + (size_t)r1 * DD))[lane];
        acc.x += s0 * v0.x + s1 * v1.x;
        acc.y += s0 * v0.y + s1 * v1.y;
        acc.z += s0 * v0.z + s1 * v1.z;
        acc.w += s0 * v0.w + s1 * v1.w;
    }
    if (e < end) {
        int r = esrc[e];
        float s = dinv[r];
        float4 v = ((const float4*)(x + (size_t)r * DD))[lane];
        acc.x += s * v.x; acc.y += s * v.y; acc.z += s * v.z; acc.w += s * v.w;
    }
    acc.x *= dc; acc.y *= dc; acc.z *= dc; acc.w *= dc;
    ((float4*)(agg + (size_t)node * DD))[lane] = acc;
}

// ---------------- fallback W -> Wt ----------------
__global__ void k_transpose_w(const float* __restrict__ W, float* __restrict__ Wt) {
    int c = blockIdx.x;
    int k = threadIdx.x;
    Wt[k * DD + c] = W[c * DD + k];
}

// ---------------- fallback vector GEMM ----------------
__global__ __launch_bounds__(256) void k_gemm(const float* __restrict__ x,
                                              const float* __restrict__ Wt,
                                              const float* __restrict__ bias,
                                              float* __restrict__ out) {
    __shared__ float wt[DD * DD];
    int t = threadIdx.x;
    for (int i = t; i < DD * DD / 4; i += 256)
        ((float4*)wt)[i] = ((const float4*)Wt)[i];
    __syncthreads();

    int grp = t >> 5;
    int c4  = (t & 31) * 4;
    int rbase = blockIdx.x * 64 + grp * 8;

    float acc[8][4];
#pragma unroll
    for (int i = 0; i < 8; i++)
#pragma unroll
        for (int j = 0; j < 4; j++) acc[i][j] = 0.0f;

    for (int k = 0; k < DD; k += 4) {
        float4 w0 = *(const float4*)&wt[(k + 0) * DD + c4];
        float4 w1 = *(const float4*)&wt[(k + 1) * DD + c4];
        float4 w2 = *(const float4*)&wt[(k + 2) * DD + c4];
        float4 w3 = *(const float4*)&wt[(k + 3) * DD + c4];
#pragma unroll
        for (int i = 0; i < 8; i++) {
            int rr = rbase + i;
            rr = rr < NN ? rr : NN - 1;
            float4 a = *(const float4*)&out[(size_t)rr * DD + k];
            acc[i][0] += a.x * w0.x + a.y * w1.x + a.z * w2.x + a.w * w3.x;
            acc[i][1] += a.x * w0.y + a.y * w1.y + a.z * w2.y + a.w * w3.y;
            acc[i][2] += a.x * w0.z + a.y * w1.z + a.z * w2.z + a.w * w3.z;
            acc[i][3] += a.x * w0.w + a.y * w1.w + a.z * w2.w + a.w * w3.w;
        }
    }

    float4 bv = *(const float4*)&bias[c4];
#pragma unroll
    for (int i = 0; i < 8; i++) {
        int r = rbase + i;
        if (r < NN) {
            float4 xv = *(const float4*)&x[(size_t)r * DD + c4];
            float4 o;
            o.x = xv.x + fmaxf(acc[i][0] + bv.x, 0.0f);
            o.y = xv.y + fmaxf(acc[i][1] + bv.y, 0.0f);
            o.z = xv.z + fmaxf(acc[i][2] + bv.z, 0.0f);
            o.w = xv.w + fmaxf(acc[i][3] + bv.w, 0.0f);
            *(float4*)&out[(size_t)r * DD + c4] = o;
        }
    }
}

extern "C" void kernel_launch(void* const* d_in, const int* in_sizes, int n_in,
                              void* d_out, int out_size, void* d_ws, size_t ws_size,
                              hipStream_t stream) {
    const float* x   = (const float*)d_in[0];
    const int*   ei  = (const int*)d_in[1];
    const float* W   = (const float*)d_in[2];
    const float* b   = (const float*)d_in[3];
    const int* row = ei;        // edge_index[0] = source
    const int* col = ei + NE;   // edge_index[1] = target

    float* out = (float*)d_out;

    // workspace layout (bytes):
    //   deg/cnt : [0,        400000)
    //   dinv    : [400000,   800000)
    //   rowptr  : [800000,  1200004)
    //   bsum    : [1200016, 1200408)
    //   boff    : [1200416, 1200808)
    //   wbs/Wt  : [1200816, 1266352)   (swizzled bf16 W / fallback Wt)
    //   esrc    : [1266352, 7666352)
    //   eslot   : [7666352, 14066352)
    //   yb      : [14066352, 39666352)
    char* ws = (char*)d_ws;
    int*   deg    = (int*)ws;
    float* dinv   = (float*)(ws + 400000);
    int*   rowptr = (int*)(ws + 800000);
    int*   bsum   = (int*)(ws + 1200016);
    int*   boff   = (int*)(ws + 1200416);
    unsigned short* wbs = (unsigned short*)(ws + 1200816);
    float* Wt     = (float*)(ws + 1200816);
    int*   esrc   = (int*)(ws + 1266352);
    int*   eslot  = (int*)(ws + 7666352);
    unsigned short* yb = (unsigned short*)(ws + 14066352);

    bool big_ws = ws_size >= 39700000;

    hipMemsetAsync(deg, 0, NN * sizeof(int), stream);

    if (big_ws) {
        k_count_slot<<<(NE + 255) / 256, 256, 0, stream>>>(col, deg, eslot);
        k_blocksum_dinv<<<NBLK, 1024, 0, stream>>>(deg, bsum, dinv);
        k_scanwrite2<<<NBLK, 1024, 0, stream>>>(deg, bsum, rowptr);
        k_wb<<<8, 256, 0, stream>>>(W, wbs);
        k_ygemm<<<(NN + 63) / 64, 256, 0, stream>>>(x, wbs, dinv, yb);
        k_fill2<<<(NE + 255) / 256, 256, 0, stream>>>(row, col, rowptr, eslot, esrc);
        k_gather_fused<<<(NN + 7) / 8, 256, 0, stream>>>(rowptr, esrc, yb, x, dinv, b, out);
    } else {
        k_count<<<(NE + 255) / 256, 256, 0, stream>>>(col, deg);
        k_blocksum_dinv<<<NBLK, 1024, 0, stream>>>(deg, bsum, dinv);
        k_scanbsum<<<1, 128, 0, stream>>>(bsum, boff);
        k_scanwrite<<<NBLK, 1024, 0, stream>>>(deg, boff, rowptr);
        hipMemsetAsync(deg, 0, NN * sizeof(int), stream);
        k_fill<<<(NE + 255) / 256, 256, 0, stream>>>(row, col, rowptr, deg, esrc);
        k_gather<<<(NN + 7) / 8, 256, 0, stream>>>(rowptr, esrc, x, dinv, out);
        k_transpose_w<<<DD, DD, 0, stream>>>(W, Wt);
        k_gemm<<<(NN + 63) / 64, 256, 0, stream>>>(x, Wt, b, out);
    }
}

// Round 8
// 187.433 us; speedup vs baseline: 15.2567x; 1.1850x over previous
//
#include <hip/hip_runtime.h>

#define NN 100000
#define NE 1600000
#define DD 128
#define NBLK 98  // ceil(NN / 1024)

typedef __attribute__((ext_vector_type(8))) short bf16x8;
typedef __attribute__((ext_vector_type(4))) float f32x4;
typedef __attribute__((ext_vector_type(2))) float f32x2;

__device__ __forceinline__ float bf2f(unsigned short u) {
    return __uint_as_float(((unsigned)u) << 16);
}
__device__ __forceinline__ unsigned short f2bf(float f) {
    unsigned u = __float_as_uint(f);
    u += 0x7FFFu + ((u >> 16) & 1u);  // round to nearest even
    return (unsigned short)(u >> 16);
}

// ---------------- degree count + per-edge slot ----------------
__global__ void k_count_slot(const int* __restrict__ col, int* __restrict__ deg,
                             int* __restrict__ eslot) {
    int i = blockIdx.x * blockDim.x + threadIdx.x;
    if (i < NE) eslot[i] = atomicAdd(&deg[col[i]], 1);
}

// plain count (fallback path)
__global__ void k_count(const int* __restrict__ col, int* __restrict__ deg) {
    int i = blockIdx.x * blockDim.x + threadIdx.x;
    if (i < NE) atomicAdd(&deg[col[i]], 1);
}

// ---------------- per-block sums + dinv ----------------
__global__ __launch_bounds__(1024) void k_blocksum_dinv(const int* __restrict__ deg,
                                                        int* __restrict__ bsum,
                                                        float* __restrict__ dinv) {
    __shared__ int red[1024];
    int t = threadIdx.x;
    int i = blockIdx.x * 1024 + t;
    int d = i < NN ? deg[i] : 0;
    if (i < NN) dinv[i] = 1.0f / sqrtf((float)(d + 1));
    red[t] = d;
    __syncthreads();
    for (int off = 512; off > 0; off >>= 1) {
        if (t < off) red[t] += red[t + off];
        __syncthreads();
    }
    if (t == 0) bsum[blockIdx.x] = red[0];
}

// ---------------- scan: every block redundantly scans bsum, then local scan ----
__global__ __launch_bounds__(1024) void k_scanwrite2(const int* __restrict__ deg,
                                                     const int* __restrict__ bsum,
                                                     int* __restrict__ rowptr) {
    __shared__ int sb[128];
    __shared__ int s[1024];
    int t = threadIdx.x;
    if (t < 128) sb[t] = t < NBLK ? bsum[t] : 0;
    __syncthreads();
    for (int off = 1; off < 128; off <<= 1) {
        int v = 0;
        if (t < 128 && t >= off) v = sb[t - off];
        __syncthreads();
        if (t < 128) sb[t] += v;
        __syncthreads();
    }
    int boff = blockIdx.x == 0 ? 0 : sb[blockIdx.x - 1];
    int i = blockIdx.x * 1024 + t;
    int v = i < NN ? deg[i] : 0;
    s[t] = v;
    __syncthreads();
    for (int off = 1; off < 1024; off <<= 1) {
        int u = t >= off ? s[t - off] : 0;
        __syncthreads();
        s[t] += u;
        __syncthreads();
    }
    if (i < NN) rowptr[i] = boff + s[t] - v;  // exclusive
    if (i == 0) rowptr[NN] = NE;
}

// fallback scan kernels
__global__ void k_scanbsum(const int* __restrict__ bsum, int* __restrict__ boff) {
    __shared__ int s[128];
    int t = threadIdx.x;
    s[t] = t < NBLK ? bsum[t] : 0;
    __syncthreads();
    for (int off = 1; off < 128; off <<= 1) {
        int v = t >= off ? s[t - off] : 0;
        __syncthreads();
        s[t] += v;
        __syncthreads();
    }
    if (t < NBLK) boff[t] = (t == 0) ? 0 : s[t - 1];
}
__global__ __launch_bounds__(1024) void k_scanwrite(const int* __restrict__ deg,
                                                    const int* __restrict__ boff,
                                                    int* __restrict__ rowptr) {
    __shared__ int s[1024];
    int t = threadIdx.x;
    int i = blockIdx.x * 1024 + t;
    int v = i < NN ? deg[i] : 0;
    s[t] = v;
    __syncthreads();
    for (int off = 1; off < 1024; off <<= 1) {
        int u = t >= off ? s[t - off] : 0;
        __syncthreads();
        s[t] += u;
        __syncthreads();
    }
    if (i < NN) rowptr[i] = boff[blockIdx.x] + s[t] - v;
    if (i == 0) rowptr[NN] = NE;
}

// ---------------- fill CSR without atomics (uses eslot) ----------------
__global__ void k_fill2(const int* __restrict__ row, const int* __restrict__ col,
                        const int* __restrict__ rowptr, const int* __restrict__ eslot,
                        int* __restrict__ esrc) {
    int i = blockIdx.x * blockDim.x + threadIdx.x;
    if (i < NE) esrc[rowptr[col[i]] + eslot[i]] = row[i];
}

// fallback fill with cursor atomics
__global__ void k_fill(const int* __restrict__ row, const int* __restrict__ col,
                       const int* __restrict__ rowptr, int* __restrict__ cnt,
                       int* __restrict__ esrc) {
    int i = blockIdx.x * blockDim.x + threadIdx.x;
    if (i < NE) {
        int c = col[i];
        int pos = rowptr[c] + atomicAdd(&cnt[c], 1);
        esrc[pos] = row[i];
    }
}

// ---------------- W -> pre-swizzled bf16 (global, 32 KB) ----------------
__global__ void k_wb(const float* __restrict__ W, unsigned short* __restrict__ wbs) {
    int unit = blockIdx.x * 256 + threadIdx.x;  // 2048 units x 8 elems
    int row = unit >> 4;                        // output-feature row
    int c0 = (unit & 15) * 8;                   // k offset
    float4 v0 = *(const float4*)(W + row * DD + c0);
    float4 v1 = *(const float4*)(W + row * DD + c0 + 4);
    bf16x8 h;
    h[0] = (short)f2bf(v0.x); h[1] = (short)f2bf(v0.y);
    h[2] = (short)f2bf(v0.z); h[3] = (short)f2bf(v0.w);
    h[4] = (short)f2bf(v1.x); h[5] = (short)f2bf(v1.y);
    h[6] = (short)f2bf(v1.z); h[7] = (short)f2bf(v1.w);
    int byte = (row * 256 + c0 * 2) ^ ((row & 7) << 4);  // XOR-swizzle
    *(bf16x8*)((char*)wbs + byte) = h;
}

// ---------------- MFMA GEMM: yb8[m] = fp8( dinv[m] * (x[m] @ W^T) ), permuted ----
// Byte p of row m holds feature n = (p&7)*16 + (p>>3)  (writer-natural order).
// Elementwise sums commute with this fixed permutation; gather un-permutes at
// its epilogue.
__global__ __launch_bounds__(256) void k_ygemm(const float* __restrict__ x,
                                               const unsigned short* __restrict__ wbs,
                                               const float* __restrict__ dinv,
                                               unsigned char* __restrict__ yb8) {
    __shared__ unsigned short wb[DD * DD];  // 32 KB, already swizzled
    int t = threadIdx.x;
#pragma unroll
    for (int i = 0; i < 8; ++i)
        ((float4*)wb)[t + 256 * i] = ((const float4*)wbs)[t + 256 * i];
    __syncthreads();

    int wave = t >> 6;
    int lane = t & 63;
    int lrow = lane & 15;   // A row within 16-tile / D col (feature n)
    int kg = lane >> 4;     // k-group 0..3

    int arow = blockIdx.x * 64 + wave * 16 + lrow;
    int arc = arow < NN ? arow : NN - 1;  // clamped rows' outputs never written
    bf16x8 afrag[4];
#pragma unroll
    for (int ks = 0; ks < 4; ++ks) {
        const float* src = x + (size_t)arc * DD + ks * 32 + kg * 8;
        float4 v0 = *(const float4*)src;
        float4 v1 = *(const float4*)(src + 4);
        bf16x8 h;
        h[0] = (short)f2bf(v0.x); h[1] = (short)f2bf(v0.y);
        h[2] = (short)f2bf(v0.z); h[3] = (short)f2bf(v0.w);
        h[4] = (short)f2bf(v1.x); h[5] = (short)f2bf(v1.y);
        h[6] = (short)f2bf(v1.z); h[7] = (short)f2bf(v1.w);
        afrag[ks] = h;
    }

    f32x4 acc[8];
#pragma unroll
    for (int ct = 0; ct < 8; ++ct) acc[ct] = (f32x4)(0.f);

#pragma unroll
    for (int ct = 0; ct < 8; ++ct) {
        int wrow = ct * 16 + lrow;  // output-feature index
#pragma unroll
        for (int ks = 0; ks < 4; ++ks) {
            int byte = (wrow * 256 + ks * 64 + kg * 16) ^ ((wrow & 7) << 4);
            bf16x8 bfrag = *(const bf16x8*)((char*)wb + byte);
            acc[ct] = __builtin_amdgcn_mfma_f32_16x16x32_bf16(afrag[ks], bfrag, acc[ct], 0, 0, 0);
        }
    }

    // epilogue: lane owns rows m = base+wave*16+kg*4+j, features n=ct*16+lrow.
    // Pack the 8 ct-values as 8 consecutive fp8 bytes at offset lrow*8.
#pragma unroll
    for (int j = 0; j < 4; ++j) {
        int m = blockIdx.x * 64 + wave * 16 + kg * 4 + j;
        if (m < NN) {
            float s = dinv[m];
            unsigned w0 = 0, w1 = 0;
            w0 = __builtin_amdgcn_cvt_pk_fp8_f32(s * acc[0][j], s * acc[1][j], w0, false);
            w0 = __builtin_amdgcn_cvt_pk_fp8_f32(s * acc[2][j], s * acc[3][j], w0, true);
            w1 = __builtin_amdgcn_cvt_pk_fp8_f32(s * acc[4][j], s * acc[5][j], w1, false);
            w1 = __builtin_amdgcn_cvt_pk_fp8_f32(s * acc[6][j], s * acc[7][j], w1, true);
            uint2 o; o.x = w0; o.y = w1;
            *(uint2*)(yb8 + (size_t)m * DD + lrow * 8) = o;
        }
    }
}

// ---------------- fused gather (fp8) + epilogue ----------------
// out[c][n] = x[c][n] + relu( dinv[c]*(yb8[c] + sum yb8[r])[p] + b[n] ),
// where lane gl accumulates permuted positions p=4gl..4gl+3, n=(p&7)*16+(p>>3).
__global__ __launch_bounds__(256) void k_gather_fp8(const int* __restrict__ rowptr,
                                                    const int* __restrict__ esrc,
                                                    const unsigned char* __restrict__ yb8,
                                                    const float* __restrict__ x,
                                                    const float* __restrict__ dinv,
                                                    const float* __restrict__ bias,
                                                    float* __restrict__ out) {
    int t = threadIdx.x;
    int gl = t & 31;
    int node = blockIdx.x * 8 + (t >> 5);
    if (node >= NN) return;
    int beg = rowptr[node];
    int end = rowptr[node + 1];
    float dc = dinv[node];

    // self term
    unsigned su = *(const unsigned*)(yb8 + (size_t)node * DD + gl * 4);
    f32x2 a01 = __builtin_amdgcn_cvt_pk_f32_fp8(su, false);
    f32x2 a23 = __builtin_amdgcn_cvt_pk_f32_fp8(su, true);

    int e = beg;
    for (; e + 7 < end; e += 8) {
        unsigned uu[8];
#pragma unroll
        for (int u = 0; u < 8; ++u) {
            int r = esrc[e + u];
            uu[u] = *(const unsigned*)(yb8 + (size_t)r * DD + gl * 4);
        }
#pragma unroll
        for (int u = 0; u < 8; ++u) {
            a01 += __builtin_amdgcn_cvt_pk_f32_fp8(uu[u], false);
            a23 += __builtin_amdgcn_cvt_pk_f32_fp8(uu[u], true);
        }
    }
    for (; e < end; ++e) {
        int r = esrc[e];
        unsigned u = *(const unsigned*)(yb8 + (size_t)r * DD + gl * 4);
        a01 += __builtin_amdgcn_cvt_pk_f32_fp8(u, false);
        a23 += __builtin_amdgcn_cvt_pk_f32_fp8(u, true);
    }

    float vals[4] = {a01.x, a01.y, a23.x, a23.y};
    int q = gl >> 1;          // p>>3 for all 4 positions
    int c0 = (gl & 1) * 4;    // (p&7) base
#pragma unroll
    for (int i = 0; i < 4; ++i) {
        int n = (c0 + i) * 16 + q;
        float h = dc * vals[i] + bias[n];
        out[(size_t)node * DD + n] = x[(size_t)node * DD + n] + fmaxf(h, 0.f);
    }
}

// ---------------- f32 fallback gather ----------------
__global__ __launch_bounds__(256) void k_gather(const int* __restrict__ rowptr,
                                                const int* __restrict__ esrc,
                                                const float* __restrict__ x,
                                                const float* __restrict__ dinv,
                                                float* __restrict__ agg) {
    int t = threadIdx.x;
    int lane = t & 31;
    int node = blockIdx.x * 8 + (t >> 5);
    if (node >= NN) return;
    int beg = rowptr[node];
    int end = rowptr[node + 1];
    float dc = dinv[node];
    float4 xv = ((const float4*)(x + (size_t)node * DD))[lane];
    float4 acc;
    acc.x = dc * xv.x; acc.y = dc * xv.y; acc.z = dc * xv.z; acc.w = dc * xv.w;
    int e = beg;
    for (; e + 1 < end; e += 2) {
        int r0 = esrc[e];
        int r1 = esrc[e + 1];
        float s0 = dinv[r0];
        float s1 = dinv[r1];
        float4 v0 = ((const float4*)(x + (size_t)r0 * DD))[lane];
        float4 v1 = ((const float4*)(x + (size_t)r1 * DD))[lane];
        acc.x += s0 * v0.x + s1 * v1.x;
        acc.y += s0 * v0.y + s1 * v1.y;
        acc.z += s0 * v0.z + s1 * v1.z;
        acc.w += s0 * v0.w + s1 * v1.w;
    }
    if (e < end) {
        int r = esrc[e];
        float s = dinv[r];
        float4 v = ((const float4*)(x + (size_t)r * DD))[lane];
        acc.x += s * v.x; acc.y += s * v.y; acc.z += s * v.z; acc.w += s * v.w;
    }
    acc.x *= dc; acc.y *= dc; acc.z *= dc; acc.w *= dc;
    ((float4*)(agg + (size_t)node * DD))[lane] = acc;
}

// ---------------- fallback W -> Wt ----------------
__global__ void k_transpose_w(const float* __restrict__ W, float* __restrict__ Wt) {
    int c = blockIdx.x;
    int k = threadIdx.x;
    Wt[k * DD + c] = W[c * DD + k];
}

// ---------------- fallback vector GEMM ----------------
__global__ __launch_bounds__(256) void k_gemm(const float* __restrict__ x,
                                              const float* __restrict__ Wt,
                                              const float* __restrict__ bias,
                                              float* __restrict__ out) {
    __shared__ float wt[DD * DD];
    int t = threadIdx.x;
    for (int i = t; i < DD * DD / 4; i += 256)
        ((float4*)wt)[i] = ((const float4*)Wt)[i];
    __syncthreads();

    int grp = t >> 5;
    int c4  = (t & 31) * 4;
    int rbase = blockIdx.x * 64 + grp * 8;

    float acc[8][4];
#pragma unroll
    for (int i = 0; i < 8; i++)
#pragma unroll
        for (int j = 0; j < 4; j++) acc[i][j] = 0.0f;

    for (int k = 0; k < DD; k += 4) {
        float4 w0 = *(const float4*)&wt[(k + 0) * DD + c4];
        float4 w1 = *(const float4*)&wt[(k + 1) * DD + c4];
        float4 w2 = *(const float4*)&wt[(k + 2) * DD + c4];
        float4 w3 = *(const float4*)&wt[(k + 3) * DD + c4];
#pragma unroll
        for (int i = 0; i < 8; i++) {
            int rr = rbase + i;
            rr = rr < NN ? rr : NN - 1;
            float4 a = *(const float4*)&out[(size_t)rr * DD + k];
            acc[i][0] += a.x * w0.x + a.y * w1.x + a.z * w2.x + a.w * w3.x;
            acc[i][1] += a.x * w0.y + a.y * w1.y + a.z * w2.y + a.w * w3.y;
            acc[i][2] += a.x * w0.z + a.y * w1.z + a.z * w2.z + a.w * w3.z;
            acc[i][3] += a.x * w0.w + a.y * w1.w + a.z * w2.w + a.w * w3.w;
        }
    }

    float4 bv = *(const float4*)&bias[c4];
#pragma unroll
    for (int i = 0; i < 8; i++) {
        int r = rbase + i;
        if (r < NN) {
            float4 xv = *(const float4*)&x[(size_t)r * DD + c4];
            float4 o;
            o.x = xv.x + fmaxf(acc[i][0] + bv.x, 0.0f);
            o.y = xv.y + fmaxf(acc[i][1] + bv.y, 0.0f);
            o.z = xv.z + fmaxf(acc[i][2] + bv.z, 0.0f);
            o.w = xv.w + fmaxf(acc[i][3] + bv.w, 0.0f);
            *(float4*)&out[(size_t)r * DD + c4] = o;
        }
    }
}

extern "C" void kernel_launch(void* const* d_in, const int* in_sizes, int n_in,
                              void* d_out, int out_size, void* d_ws, size_t ws_size,
                              hipStream_t stream) {
    const float* x   = (const float*)d_in[0];
    const int*   ei  = (const int*)d_in[1];
    const float* W   = (const float*)d_in[2];
    const float* b   = (const float*)d_in[3];
    const int* row = ei;        // edge_index[0] = source
    const int* col = ei + NE;   // edge_index[1] = target

    float* out = (float*)d_out;

    // workspace layout (bytes):
    //   deg/cnt : [0,        400000)
    //   dinv    : [400000,   800000)
    //   rowptr  : [800000,  1200004)
    //   bsum    : [1200016, 1200408)
    //   boff    : [1200416, 1200808)
    //   wbs/Wt  : [1200816, 1266352)   (swizzled bf16 W / fallback Wt)
    //   esrc    : [1266352, 7666352)
    //   eslot   : [7666352, 14066352)
    //   yb8     : [14066352, 26866352)
    char* ws = (char*)d_ws;
    int*   deg    = (int*)ws;
    float* dinv   = (float*)(ws + 400000);
    int*   rowptr = (int*)(ws + 800000);
    int*   bsum   = (int*)(ws + 1200016);
    int*   boff   = (int*)(ws + 1200416);
    unsigned short* wbs = (unsigned short*)(ws + 1200816);
    float* Wt     = (float*)(ws + 1200816);
    int*   esrc   = (int*)(ws + 1266352);
    int*   eslot  = (int*)(ws + 7666352);
    unsigned char* yb8 = (unsigned char*)(ws + 14066352);

    bool big_ws = ws_size >= 26900000;

    hipMemsetAsync(deg, 0, NN * sizeof(int), stream);

    if (big_ws) {
        k_count_slot<<<(NE + 255) / 256, 256, 0, stream>>>(col, deg, eslot);
        k_blocksum_dinv<<<NBLK, 1024, 0, stream>>>(deg, bsum, dinv);
        k_scanwrite2<<<NBLK, 1024, 0, stream>>>(deg, bsum, rowptr);
        k_wb<<<8, 256, 0, stream>>>(W, wbs);
        k_ygemm<<<(NN + 63) / 64, 256, 0, stream>>>(x, wbs, dinv, yb8);
        k_fill2<<<(NE + 255) / 256, 256, 0, stream>>>(row, col, rowptr, eslot, esrc);
        k_gather_fp8<<<(NN + 7) / 8, 256, 0, stream>>>(rowptr, esrc, yb8, x, dinv, b, out);
    } else {
        k_count<<<(NE + 255) / 256, 256, 0, stream>>>(col, deg);
        k_blocksum_dinv<<<NBLK, 1024, 0, stream>>>(deg, bsum, dinv);
        k_scanbsum<<<1, 128, 0, stream>>>(bsum, boff);
        k_scanwrite<<<NBLK, 1024, 0, stream>>>(deg, boff, rowptr);
        hipMemsetAsync(deg, 0, NN * sizeof(int), stream);
        k_fill<<<(NE + 255) / 256, 256, 0, stream>>>(row, col, rowptr, deg, esrc);
        k_gather<<<(NN + 7) / 8, 256, 0, stream>>>(rowptr, esrc, x, dinv, out);
        k_transpose_w<<<DD, DD, 0, stream>>>(W, Wt);
        k_gemm<<<(NN + 63) / 64, 256, 0, stream>>>(x, Wt, b, out);
    }
}